// Round 4
// baseline (345.107 us; speedup 1.0000x reference)
//
#include <hip/hip_runtime.h>
#include <hip/hip_bf16.h>
#include <stdint.h>

#define B_ 8
#define T_ 2048
#define C_ 384
#define H_ 6
#define D_ 64
#define M_ (B_*T_)   // 16384

typedef unsigned short u16;
typedef unsigned int u32;
typedef __attribute__((ext_vector_type(8))) short short8;
typedef __attribute__((ext_vector_type(4))) float floatx4;
typedef __attribute__((ext_vector_type(16))) float floatx16;

// softmax scale folded into stored Q: 0.125 * log2(e)
#define QSCALE 0.18033688011112042f

__device__ __forceinline__ u16 f2b(float f) {
  union { float f; unsigned u; } x; x.f = f;
  unsigned r = x.u + 0x7fffu + ((x.u >> 16) & 1u);  // round-nearest-even
  return (u16)(r >> 16);
}
__device__ __forceinline__ u32 pack_bf16(float a, float b) {
  union { __hip_bfloat162 h; u32 u; } x;
  x.h = __float22bfloat162_rn(float2{a, b});
  return x.u;
}
__device__ __forceinline__ uint4 pack8(const float4& lo, const float4& hi) {
  uint4 r;
  r.x = pack_bf16(lo.x, lo.y); r.y = pack_bf16(lo.z, lo.w);
  r.z = pack_bf16(hi.x, hi.y); r.w = pack_bf16(hi.z, hi.w);
  return r;
}

// v_permlane32_swap_b32: swaps a.hi(32 lanes) <-> b.lo(32 lanes).
__device__ __forceinline__ void plswap(u32& a, u32& b) {
  asm("v_permlane32_swap_b32 %0, %1" : "+v"(a), "+v"(b));
}

// ---------------------------------------------------------------------------
// Fused QKV projection.  XCD-locality remap: the 6 head-blocks of one
// m-block run on the same XCD so X rows are fetched once per XCD L2.
// ---------------------------------------------------------------------------
__global__ __launch_bounds__(256) void qkv_fused(
    const float* __restrict__ Xf,
    const float* __restrict__ Wqf, const float* __restrict__ Wkf, const float* __restrict__ Wvf,
    const float* __restrict__ cosb, const float* __restrict__ sinb,
    u16* __restrict__ Qo, u16* __restrict__ Ko, u16* __restrict__ Vto)
{
  __shared__ __align__(16) u16 smem[128 * 64 + 3 * 64 * 64];  // As | Bs[3] (40 KB)
  u16* As = smem;
  u16* Bs0 = smem + 128 * 64;

  // XCD remap: 768 wgs = 8 xcds x (16 m-blocks x 6 heads)
  const int id = blockIdx.x;
  const int xcd = id & 7;
  const int s = id >> 3;              // 0..95
  const int mb = xcd * 16 + s / 6;    // 0..127 (6 consecutive slots share mb)
  const int hh = s % 6;
  const int m0 = mb * 128;
  const int n0 = hh * 64;

  const int tid = threadIdx.x;
  const int w = tid >> 6;
  const int lane = tid & 63;
  const int quad = lane >> 4;
  const int c = lane & 15;

  const float* Wz[3] = {Wqf, Wkf, Wvf};

  floatx4 acc[3][2][4];
#pragma unroll
  for (int z = 0; z < 3; z++)
#pragma unroll
    for (int i = 0; i < 2; i++)
#pragma unroll
      for (int j = 0; j < 4; j++) acc[z][i][j] = (floatx4){0.f, 0.f, 0.f, 0.f};

  const int ra = tid >> 1, ca = (tid & 1) * 4;   // A: 2 thr/row, 4 chunks each
  const int rb = tid >> 2, cb = (tid & 3) * 2;   // B: 4 thr/row, 2 chunks each

  for (int k0 = 0; k0 < 384; k0 += 64) {
    float4 af[8];
#pragma unroll
    for (int j = 0; j < 4; j++) {
      const float* p = Xf + (size_t)(m0 + ra) * C_ + k0 + (ca + j) * 8;
      af[2 * j]     = *reinterpret_cast<const float4*>(p);
      af[2 * j + 1] = *reinterpret_cast<const float4*>(p + 4);
    }
    float4 bw[3][4];
#pragma unroll
    for (int z = 0; z < 3; z++)
#pragma unroll
      for (int u = 0; u < 2; u++) {
        const float* p = Wz[z] + (size_t)(n0 + rb) * C_ + k0 + (cb + u) * 8;
        bw[z][2 * u]     = *reinterpret_cast<const float4*>(p);
        bw[z][2 * u + 1] = *reinterpret_cast<const float4*>(p + 4);
      }
    __syncthreads();
#pragma unroll
    for (int j = 0; j < 4; j++)
      *reinterpret_cast<uint4*>(As + ra * 64 + (((ca + j) ^ (ra & 7)) * 8)) =
          pack8(af[2 * j], af[2 * j + 1]);
#pragma unroll
    for (int z = 0; z < 3; z++)
#pragma unroll
      for (int u = 0; u < 2; u++)
        *reinterpret_cast<uint4*>(Bs0 + z * 4096 + rb * 64 + (((cb + u) ^ (rb & 7)) * 8)) =
            pack8(bw[z][2 * u], bw[z][2 * u + 1]);
    __syncthreads();

#pragma unroll
    for (int ks = 0; ks < 2; ks++) {
      short8 af2[2];
#pragma unroll
      for (int mi = 0; mi < 2; mi++) {
        int row = w * 32 + mi * 16 + c;
        af2[mi] = *reinterpret_cast<const short8*>(
            As + row * 64 + (((ks * 4 + quad) ^ (row & 7)) * 8));
      }
#pragma unroll
      for (int z = 0; z < 3; z++) {
#pragma unroll
        for (int ni = 0; ni < 4; ni++) {
          int row = ni * 16 + c;
          short8 bf = *reinterpret_cast<const short8*>(
              Bs0 + z * 4096 + row * 64 + (((ks * 4 + quad) ^ (row & 7)) * 8));
#pragma unroll
          for (int mi = 0; mi < 2; mi++)
            acc[z][mi][ni] = __builtin_amdgcn_mfma_f32_16x16x32_bf16(af2[mi], bf, acc[z][mi][ni], 0, 0, 0);
        }
      }
    }
  }

  const int bb2 = m0 >> 11;
  const int tbase = m0 & (T_ - 1);

  // ---- V: register scatter to Vt[B][H][D][T] ----
  {
    const size_t vbase = ((size_t)(bb2 * H_ + hh)) * D_ * T_;
#pragma unroll
    for (int mi = 0; mi < 2; mi++) {
      int t = tbase + w * 32 + mi * 16 + quad * 4;
#pragma unroll
      for (int ni = 0; ni < 4; ni++) {
        int d = ni * 16 + c;
        ushort4 pk;
        pk.x = f2b(acc[2][mi][ni][0]); pk.y = f2b(acc[2][mi][ni][1]);
        pk.z = f2b(acc[2][mi][ni][2]); pk.w = f2b(acc[2][mi][ni][3]);
        *reinterpret_cast<ushort4*>(Vto + vbase + (size_t)d * T_ + t) = pk;
      }
    }
  }

  // ---- Q then K: lane-parallel RMS + RoPE, LDS transpose store ----
  u16* Ep = smem;
#pragma unroll
  for (int zz = 0; zz < 2; zz++) {
    __syncthreads();
#pragma unroll
    for (int mi = 0; mi < 2; mi++) {
      float ssr[4];
#pragma unroll
      for (int r = 0; r < 4; r++) {
        float s0 = acc[zz][mi][0][r], s1 = acc[zz][mi][1][r];
        float s2 = acc[zz][mi][2][r], s3 = acc[zz][mi][3][r];
        ssr[r] = s0 * s0 + s1 * s1 + s2 * s2 + s3 * s3;
      }
#pragma unroll
      for (int off = 1; off < 16; off <<= 1)
#pragma unroll
        for (int r = 0; r < 4; r++) ssr[r] += __shfl_xor(ssr[r], off, 64);
      int rowb = w * 32 + mi * 16 + quad * 4;
#pragma unroll
      for (int r = 0; r < 4; r++) {
        float scl = rsqrtf(ssr[r] * (1.0f / 64.0f) + 1e-5f);
        if (zz == 0) scl *= QSCALE;     // fold softmax scale into Q
        int t = tbase + rowb + r;
#pragma unroll
        for (int h2 = 0; h2 < 2; h2++) {
          float cs = cosb[t * 32 + h2 * 16 + c];
          float sn = sinb[t * 32 + h2 * 16 + c];
          float x1 = acc[zz][mi][h2][r];
          float x2 = acc[zz][mi][h2 + 2][r];
          Ep[(rowb + r) * 72 + h2 * 16 + c]       = f2b((x1 * cs + x2 * sn) * scl);
          Ep[(rowb + r) * 72 + (h2 + 2) * 16 + c] = f2b((x2 * cs - x1 * sn) * scl);
        }
      }
    }
    __syncthreads();
    {
      int row = tid >> 1, half = tid & 1;
      int t = tbase + row;
      u16* Og = (zz == 0) ? Qo : Ko;
      u16* dst = Og + (((size_t)(bb2 * H_ + hh)) * T_ + t) * D_ + half * 32;
#pragma unroll
      for (int i = 0; i < 4; i++)
        *reinterpret_cast<uint4*>(dst + i * 8) =
            *reinterpret_cast<const uint4*>(Ep + row * 72 + half * 32 + i * 8);
    }
  }
}

// ---------------------------------------------------------------------------
// MFMA flash attention — round 4: ZERO LDS / ZERO BARRIERS in the main loop.
// K+V^T per bh = 512 KB, L2-resident per XCD (6 bh = 3 MB < 4 MB) and each
// tile's 16 KB is L1-resident across the block's 4 waves -> read K/V
// fragments directly per-lane from global.  The LDS fragment pattern had a
// STRUCTURAL 4-way bank conflict (row stride 128 B == 0 mod banks; 32 lanes
// over 8 slots) — identical conflict counts across 3 swizzles proved it.
// Register pipeline: V(i) issued before QK^T(i) (covered by K-wait);
// K(i+1) issued before softmax (exp+cvt+PV ~400 cyc covers ~200 cyc L2 hit).
// vmcnt never drains to 0; waves drift freely (no convoy).
// ---------------------------------------------------------------------------
__global__ __launch_bounds__(256, 2) void attn_mfma(
    const u16* __restrict__ Qg, const u16* __restrict__ Kg,
    const u16* __restrict__ Vtg, u16* __restrict__ Yg)
{
  __shared__ __align__(16) u16 smem[9216];   // epilogue transpose only (18 KB)

  const int tid = threadIdx.x;
  const int w = tid >> 6;
  const int lane = tid & 63;
  const int hi = lane >> 5;     // k-slot half
  const int lq = lane & 31;     // q (QK^T out col / O col d / K row / V^T row)

  // XCD remap: 768 wgs = 8 xcds x (6 bh x 16 q-blocks)
  const int id = blockIdx.x;
  const int xcd = id & 7;
  const int slot = id >> 3;              // 0..95
  const int bh = xcd * 6 + (slot >> 4);  // 0..47
  const int q0 = (slot & 15) * 128;

  const size_t baseQK = (size_t)bh * T_ * D_;
  const size_t baseV  = (size_t)bh * D_ * T_;

  // Q fragments (B-operand): lane holds Q[q0+w*32+lq][ds*16 + hi*8 + j]
  short8 qf[4];
  {
    const u16* qp = Qg + baseQK + (size_t)(q0 + w * 32 + lq) * D_ + hi * 8;
#pragma unroll
    for (int d = 0; d < 4; d++)
      qf[d] = *reinterpret_cast<const short8*>(qp + d * 16);
  }

  floatx16 z16;
#pragma unroll
  for (int i = 0; i < 16; i++) z16[i] = 0.f;
  short8 vones;
#pragma unroll
  for (int i = 0; i < 8; i++) vones[i] = (short)0x3F80;

  // per-lane fragment base pointers (advance per tile)
  const u16* kptr = Kg + baseQK + (size_t)lq * D_ + hi * 8;   // K row lq
  const u16* vptr = Vtg + baseV + (size_t)lq * T_ + hi * 8;   // V^T row d=lq

  floatx16 o0 = z16, o1 = z16;
  floatx16 l_acc = z16;

  // prologue: K fragments for tile 0
  short8 kreg[2][4];
#pragma unroll
  for (int tt = 0; tt < 2; tt++)
#pragma unroll
    for (int ds = 0; ds < 4; ds++)
      kreg[tt][ds] = *reinterpret_cast<const short8*>(
          kptr + (size_t)(tt * 32) * D_ + ds * 16);

  for (int kt = 0; kt < T_; kt += 64) {
    // issue V loads for THIS tile (PV waits on these; K(i+1) stays in flight)
    short8 vreg[2][4];
#pragma unroll
    for (int nt = 0; nt < 2; nt++)
#pragma unroll
      for (int ks = 0; ks < 4; ks++)
        vreg[nt][ks] = *reinterpret_cast<const short8*>(
            vptr + (size_t)(nt * 32) * T_ + ks * 16);
    vptr += 64;

    // ---- QK^T (swapped): st = K * Q^T, col = q (lane-local), rows = t ----
    floatx16 st0, st1;
    __builtin_amdgcn_s_setprio(1);
    st0 = __builtin_amdgcn_mfma_f32_32x32x16_bf16(kreg[0][0], qf[0], z16, 0, 0, 0);
    st1 = __builtin_amdgcn_mfma_f32_32x32x16_bf16(kreg[1][0], qf[0], z16, 0, 0, 0);
#pragma unroll
    for (int ds = 1; ds < 4; ds++) {
      st0 = __builtin_amdgcn_mfma_f32_32x32x16_bf16(kreg[0][ds], qf[ds], st0, 0, 0, 0);
      st1 = __builtin_amdgcn_mfma_f32_32x32x16_bf16(kreg[1][ds], qf[ds], st1, 0, 0, 0);
    }
    __builtin_amdgcn_s_setprio(0);

    // prefetch K fragments for NEXT tile (latency covered by exp+cvt+PV)
    if (kt + 64 < T_) {
      kptr += (size_t)64 * D_;
#pragma unroll
      for (int tt = 0; tt < 2; tt++)
#pragma unroll
        for (int ds = 0; ds < 4; ds++)
          kreg[tt][ds] = *reinterpret_cast<const short8*>(
              kptr + (size_t)(tt * 32) * D_ + ds * 16);
    }

    // ---- softmax: p = exp2(s)  (scale folded into Q, bias cancels) ----
#pragma unroll
    for (int r = 0; r < 16; r++) {
      st0[r] = exp2f(st0[r]);
      st1[r] = exp2f(st1[r]);
    }

    // ---- P -> bf16 A-fragments: 16 cvt_pk + 8 permlane32_swap ----
    short8 pa[4];
#pragma unroll
    for (int ks = 0; ks < 4; ks++) {
      const floatx16& s = (ks < 2) ? st0 : st1;
      const int rb = (ks & 1) * 8;
      u32 ca = pack_bf16(s[rb + 0], s[rb + 1]);
      u32 cb = pack_bf16(s[rb + 2], s[rb + 3]);
      u32 cc = pack_bf16(s[rb + 4], s[rb + 5]);
      u32 cd = pack_bf16(s[rb + 6], s[rb + 7]);
      plswap(ca, cc);
      plswap(cb, cd);
      short8 pf;
      u32* pfu = reinterpret_cast<u32*>(&pf);
      pfu[0] = ca; pfu[1] = cb; pfu[2] = cc; pfu[3] = cd;
      pa[ks] = pf;
    }

    // ---- PV + l row-sums (B = V^T fragments from regs) ----
    __builtin_amdgcn_s_setprio(1);
#pragma unroll
    for (int ks = 0; ks < 4; ks++) {
      o0 = __builtin_amdgcn_mfma_f32_32x32x16_bf16(pa[ks], vreg[0][ks], o0, 0, 0, 0);
      o1 = __builtin_amdgcn_mfma_f32_32x32x16_bf16(pa[ks], vreg[1][ks], o1, 0, 0, 0);
    }
#pragma unroll
    for (int ks = 0; ks < 4; ks++)
      l_acc = __builtin_amdgcn_mfma_f32_32x32x16_bf16(pa[ks], vones, l_acc, 0, 0, 0);
    __builtin_amdgcn_s_setprio(0);
  }

  // normalization: l_acc[r] holds l for exactly the q-row o[r] holds
  float invr[16];
#pragma unroll
  for (int r = 0; r < 16; r++) invr[r] = __builtin_amdgcn_rcpf(l_acc[r]);

  // epilogue: LDS transpose (row = q-local, col = d) then coalesced stores
  u16* Ep = smem + w * (32 * 72);
#pragma unroll
  for (int nt = 0; nt < 2; nt++) {
    const floatx16& o = nt ? o1 : o0;
#pragma unroll
    for (int r = 0; r < 16; r++) {
      const int rl = (r & 3) + 8 * (r >> 2) + 4 * hi;
      Ep[rl * 72 + nt * 32 + lq] = f2b(o[r] * invr[r]);
    }
  }
  __syncthreads();
  {
    const int row = tid >> 1, half = tid & 1;   // 128 rows x 2 halves of 64B
    const u16* src = smem + (row >> 5) * (32 * 72) + (row & 31) * 72 + half * 32;
    const int t = q0 + row;
    const int b = bh / H_, h = bh % H_;
    const size_t yi = ((size_t)b * T_ + t) * C_ + (size_t)h * 64 + half * 32;
#pragma unroll
    for (int i = 0; i < 4; i++)
      *reinterpret_cast<uint4*>(Yg + yi + i * 8) =
          *reinterpret_cast<const uint4*>(src + i * 8);
  }
}

// ---------------------------------------------------------------------------
// Out projection.  XCD-locality remap: the 6 col-blocks of one m-block share
// an XCD so Y rows are fetched once per XCD L2.
// ---------------------------------------------------------------------------
__global__ __launch_bounds__(256) void out_mfma(
    const u16* __restrict__ Xb, const float* __restrict__ Wf, float* __restrict__ Og)
{
  __shared__ __align__(16) u16 smem[17408];   // As|Bs, then fp32 Ep (34816 B)
  u16* As = smem;
  u16* Bs = smem + 128 * 64;

  const int id = blockIdx.x;
  const int xcd = id & 7;
  const int s = id >> 3;              // 0..95
  const int m0 = (xcd * 16 + s / 6) * 128;
  const int n0 = (s % 6) * 64;

  const int tid = threadIdx.x;
  const int w = tid >> 6;
  const int lane = tid & 63;
  const int quad = lane >> 4;
  const int c = lane & 15;

  floatx4 acc[2][4];
#pragma unroll
  for (int i = 0; i < 2; i++)
#pragma unroll
    for (int j = 0; j < 4; j++) acc[i][j] = (floatx4){0.f, 0.f, 0.f, 0.f};

  const int ra = tid >> 1, ca = (tid & 1) * 4;
  const int rb = tid >> 2, cb = (tid & 3) * 2;

  for (int k0 = 0; k0 < 384; k0 += 64) {
    uint4 a[4];
#pragma unroll
    for (int j = 0; j < 4; j++)
      a[j] = *reinterpret_cast<const uint4*>(Xb + (size_t)(m0 + ra) * C_ + k0 + (ca + j) * 8);
    float4 bw[4];
#pragma unroll
    for (int u = 0; u < 2; u++) {
      const float* p = Wf + (size_t)(n0 + rb) * C_ + k0 + (cb + u) * 8;
      bw[2 * u]     = *reinterpret_cast<const float4*>(p);
      bw[2 * u + 1] = *reinterpret_cast<const float4*>(p + 4);
    }
    __syncthreads();
#pragma unroll
    for (int j = 0; j < 4; j++)
      *reinterpret_cast<uint4*>(As + ra * 64 + (((ca + j) ^ (ra & 7)) * 8)) = a[j];
#pragma unroll
    for (int u = 0; u < 2; u++)
      *reinterpret_cast<uint4*>(Bs + rb * 64 + (((cb + u) ^ (rb & 7)) * 8)) =
          pack8(bw[2 * u], bw[2 * u + 1]);
    __syncthreads();

#pragma unroll
    for (int ks = 0; ks < 2; ks++) {
      short8 af[2], bf[4];
#pragma unroll
      for (int mi = 0; mi < 2; mi++) {
        int row = w * 32 + mi * 16 + c;
        af[mi] = *reinterpret_cast<const short8*>(
            As + row * 64 + (((ks * 4 + quad) ^ (row & 7)) * 8));
      }
#pragma unroll
      for (int ni = 0; ni < 4; ni++) {
        int row = ni * 16 + c;
        bf[ni] = *reinterpret_cast<const short8*>(
            Bs + row * 64 + (((ks * 4 + quad) ^ (row & 7)) * 8));
      }
#pragma unroll
      for (int mi = 0; mi < 2; mi++)
#pragma unroll
        for (int ni = 0; ni < 4; ni++)
          acc[mi][ni] = __builtin_amdgcn_mfma_f32_16x16x32_bf16(af[mi], bf[ni], acc[mi][ni], 0, 0, 0);
    }
  }

  __syncthreads();
  float* Ep = reinterpret_cast<float*>(smem) + w * (32 * 68);
#pragma unroll
  for (int mi = 0; mi < 2; mi++)
#pragma unroll
    for (int ni = 0; ni < 4; ni++) {
      int rw = mi * 16 + quad * 4;
      int col = ni * 16 + c;
#pragma unroll
      for (int r = 0; r < 4; r++)
        Ep[(rw + r) * 68 + col] = acc[mi][ni][r];
    }
  __syncthreads();
  {
    int rw2 = lane >> 1, half = lane & 1;
    const float* src = Ep + rw2 * 68 + half * 32;
    float* dst = Og + (size_t)(m0 + w * 32 + rw2) * C_ + n0 + half * 32;
#pragma unroll
    for (int i = 0; i < 8; i++)
      *reinterpret_cast<float4*>(dst + i * 4) =
          *reinterpret_cast<const float4*>(src + i * 4);
  }
}

// ---------------------------------------------------------------------------
extern "C" void kernel_launch(void* const* d_in, const int* in_sizes, int n_in,
                              void* d_out, int out_size, void* d_ws, size_t ws_size,
                              hipStream_t stream) {
  (void)in_sizes; (void)n_in; (void)out_size; (void)ws_size;
  const float* x    = (const float*)d_in[0];
  const float* Wq   = (const float*)d_in[1];
  const float* Wk   = (const float*)d_in[2];
  const float* Wv   = (const float*)d_in[3];
  const float* Wo   = (const float*)d_in[4];
  const float* cosb = (const float*)d_in[5];
  const float* sinb = (const float*)d_in[6];

  const size_t MC = (size_t)M_ * C_;    // 6291456
  u16* ws = (u16*)d_ws;
  u16* Q   = ws;                        // [B][H][T][D] bf16 (pre-scaled)
  u16* K   = Q + MC;
  u16* Vt  = K + MC;                    // [B][H][D][T] bf16
  u16* Y   = Vt + MC;                   // [B*T][C] bf16
  float* out = (float*)d_out;

  qkv_fused<<<768, 256, 0, stream>>>(x, Wq, Wk, Wv, cosb, sinb, Q, K, Vt);

  attn_mfma<<<768, 256, 0, stream>>>(Q, K, Vt, Y);

  out_mfma<<<768, 256, 0, stream>>>(Y, Wo, out);
}

// Round 5
// 239.139 us; speedup vs baseline: 1.4431x; 1.4431x over previous
//
#include <hip/hip_runtime.h>
#include <hip/hip_bf16.h>
#include <stdint.h>

#define B_ 8
#define T_ 2048
#define C_ 384
#define H_ 6
#define D_ 64
#define M_ (B_*T_)   // 16384

typedef unsigned short u16;
typedef unsigned int u32;
typedef __attribute__((ext_vector_type(8))) short short8;
typedef __attribute__((ext_vector_type(4))) float floatx4;
typedef __attribute__((ext_vector_type(16))) float floatx16;

// softmax scale folded into stored Q: 0.125 * log2(e)
#define QSCALE 0.18033688011112042f

__device__ __forceinline__ u16 f2b(float f) {
  union { float f; unsigned u; } x; x.f = f;
  unsigned r = x.u + 0x7fffu + ((x.u >> 16) & 1u);  // round-nearest-even
  return (u16)(r >> 16);
}
__device__ __forceinline__ u32 pack_bf16(float a, float b) {
  union { __hip_bfloat162 h; u32 u; } x;
  x.h = __float22bfloat162_rn(float2{a, b});
  return x.u;
}
__device__ __forceinline__ uint4 pack8(const float4& lo, const float4& hi) {
  uint4 r;
  r.x = pack_bf16(lo.x, lo.y); r.y = pack_bf16(lo.z, lo.w);
  r.z = pack_bf16(hi.x, hi.y); r.w = pack_bf16(hi.z, hi.w);
  return r;
}

// v_permlane32_swap_b32: swaps a.hi(32 lanes) <-> b.lo(32 lanes).
__device__ __forceinline__ void plswap(u32& a, u32& b) {
  asm("v_permlane32_swap_b32 %0, %1" : "+v"(a), "+v"(b));
}

// async global->LDS, 16B per lane.  LDS dest is wave-uniform base + lane*16;
// global src is per-lane.  Drained by the compiler's waitcnt before s_barrier.
__device__ __forceinline__ void gl_lds16(const u16* g, u16* l) {
#if __has_builtin(__builtin_amdgcn_global_load_lds)
  __builtin_amdgcn_global_load_lds(
      (const __attribute__((address_space(1))) unsigned int*)g,
      (__attribute__((address_space(3))) unsigned int*)l,
      16, 0, 0);
#else
  *reinterpret_cast<uint4*>(l + (threadIdx.x & 63) * 8) =
      *reinterpret_cast<const uint4*>(g);
#endif
}

// ---------------------------------------------------------------------------
// prep: one-time fp32 -> bf16 conversion of X and the four weight matrices.
// 860160 chunks of 8 elems = 3360 blocks x 256 threads, one chunk each.
// ---------------------------------------------------------------------------
__global__ __launch_bounds__(256) void prep_bf16(
    const float* __restrict__ x,
    const float* __restrict__ wq, const float* __restrict__ wk,
    const float* __restrict__ wv, const float* __restrict__ wo,
    u16* __restrict__ xb,
    u16* __restrict__ wqb, u16* __restrict__ wkb,
    u16* __restrict__ wvb, u16* __restrict__ wob)
{
  const int c = blockIdx.x * 256 + threadIdx.x;
  const float* src;
  u16* dst;
  int off;
  if (c < 786432) {                 // X: 6291456 / 8
    src = x; dst = xb; off = c;
  } else {
    int t = c - 786432;             // W: 147456 / 8 = 18432 chunks each
    int wsel = t / 18432;
    off = t - wsel * 18432;
    src = (wsel == 0) ? wq : (wsel == 1) ? wk : (wsel == 2) ? wv : wo;
    dst = (wsel == 0) ? wqb : (wsel == 1) ? wkb : (wsel == 2) ? wvb : wob;
  }
  const float4* p = reinterpret_cast<const float4*>(src + (size_t)off * 8);
  float4 lo = p[0], hi = p[1];
  *reinterpret_cast<uint4*>(dst + (size_t)off * 8) = pack8(lo, hi);
}

// ---------------------------------------------------------------------------
// Fused QKV projection — round 5: pure-bf16 operands, global_load_lds
// width-16 staging (no staging VGPRs, no pack VALU in the k-loop), linear
// LDS layout.  XCD-locality remap unchanged (X rows fetched once per XCD).
// ---------------------------------------------------------------------------
__global__ __launch_bounds__(256) void qkv_fused(
    const u16* __restrict__ Xb,
    const u16* __restrict__ Wqb, const u16* __restrict__ Wkb, const u16* __restrict__ Wvb,
    const float* __restrict__ cosb, const float* __restrict__ sinb,
    u16* __restrict__ Qo, u16* __restrict__ Ko, u16* __restrict__ Vto)
{
  __shared__ __align__(16) u16 smem[128 * 64 + 3 * 64 * 64];  // As | Bs[3] (40 KB)
  u16* As = smem;
  u16* Bs0 = smem + 128 * 64;

  // XCD remap: 768 wgs = 8 xcds x (16 m-blocks x 6 heads)
  const int id = blockIdx.x;
  const int xcd = id & 7;
  const int s = id >> 3;              // 0..95
  const int mb = xcd * 16 + s / 6;    // 0..127
  const int hh = s % 6;
  const int m0 = mb * 128;
  const int n0 = hh * 64;

  const int tid = threadIdx.x;
  const int w = tid >> 6;
  const int lane = tid & 63;
  const int quad = lane >> 4;
  const int c = lane & 15;

  const u16* Wz[3] = {Wqb, Wkb, Wvb};

  floatx4 acc[3][2][4];
#pragma unroll
  for (int z = 0; z < 3; z++)
#pragma unroll
    for (int i = 0; i < 2; i++)
#pragma unroll
      for (int j = 0; j < 4; j++) acc[z][i][j] = (floatx4){0.f, 0.f, 0.f, 0.f};

  const int lrow = lane >> 3;        // row within an 8-row chunk
  const int lcol = (lane & 7) * 8;   // 8-col (16B) offset

  for (int k0 = 0; k0 < 384; k0 += 64) {
    __syncthreads();   // prior MFMA reads complete before overwrite
    // A: 16 chunks of 1 KB (8 rows x 64 cols); wave w stages 4
#pragma unroll
    for (int n = 0; n < 4; n++) {
      const int ch = w * 4 + n;
      gl_lds16(Xb + (size_t)(m0 + ch * 8 + lrow) * C_ + k0 + lcol, As + ch * 512);
    }
    // B: 3 x 8 chunks; wave w stages 2 per z
#pragma unroll
    for (int z = 0; z < 3; z++)
#pragma unroll
      for (int n = 0; n < 2; n++) {
        const int ch = w * 2 + n;
        gl_lds16(Wz[z] + (size_t)(n0 + ch * 8 + lrow) * C_ + k0 + lcol,
                 Bs0 + z * 4096 + ch * 512);
      }
    __syncthreads();   // implicit vmcnt(0) drain -> LDS ready

#pragma unroll
    for (int ks = 0; ks < 2; ks++) {
      short8 af2[2];
#pragma unroll
      for (int mi = 0; mi < 2; mi++)
        af2[mi] = *reinterpret_cast<const short8*>(
            As + (w * 32 + mi * 16 + c) * 64 + (ks * 4 + quad) * 8);
#pragma unroll
      for (int z = 0; z < 3; z++) {
#pragma unroll
        for (int ni = 0; ni < 4; ni++) {
          short8 bf = *reinterpret_cast<const short8*>(
              Bs0 + z * 4096 + (ni * 16 + c) * 64 + (ks * 4 + quad) * 8);
#pragma unroll
          for (int mi = 0; mi < 2; mi++)
            acc[z][mi][ni] = __builtin_amdgcn_mfma_f32_16x16x32_bf16(af2[mi], bf, acc[z][mi][ni], 0, 0, 0);
        }
      }
    }
  }

  const int bb2 = m0 >> 11;
  const int tbase = m0 & (T_ - 1);

  // ---- V: register scatter to Vt[B][H][D][T] ----
  {
    const size_t vbase = ((size_t)(bb2 * H_ + hh)) * D_ * T_;
#pragma unroll
    for (int mi = 0; mi < 2; mi++) {
      int t = tbase + w * 32 + mi * 16 + quad * 4;
#pragma unroll
      for (int ni = 0; ni < 4; ni++) {
        int d = ni * 16 + c;
        ushort4 pk;
        pk.x = f2b(acc[2][mi][ni][0]); pk.y = f2b(acc[2][mi][ni][1]);
        pk.z = f2b(acc[2][mi][ni][2]); pk.w = f2b(acc[2][mi][ni][3]);
        *reinterpret_cast<ushort4*>(Vto + vbase + (size_t)d * T_ + t) = pk;
      }
    }
  }

  // ---- Q then K: lane-parallel RMS + RoPE, LDS transpose store ----
  u16* Ep = smem;
#pragma unroll
  for (int zz = 0; zz < 2; zz++) {
    __syncthreads();
#pragma unroll
    for (int mi = 0; mi < 2; mi++) {
      float ssr[4];
#pragma unroll
      for (int r = 0; r < 4; r++) {
        float s0 = acc[zz][mi][0][r], s1 = acc[zz][mi][1][r];
        float s2 = acc[zz][mi][2][r], s3 = acc[zz][mi][3][r];
        ssr[r] = s0 * s0 + s1 * s1 + s2 * s2 + s3 * s3;
      }
#pragma unroll
      for (int off = 1; off < 16; off <<= 1)
#pragma unroll
        for (int r = 0; r < 4; r++) ssr[r] += __shfl_xor(ssr[r], off, 64);
      int rowb = w * 32 + mi * 16 + quad * 4;
#pragma unroll
      for (int r = 0; r < 4; r++) {
        float scl = rsqrtf(ssr[r] * (1.0f / 64.0f) + 1e-5f);
        if (zz == 0) scl *= QSCALE;     // fold softmax scale into Q
        int t = tbase + rowb + r;
#pragma unroll
        for (int h2 = 0; h2 < 2; h2++) {
          float cs = cosb[t * 32 + h2 * 16 + c];
          float sn = sinb[t * 32 + h2 * 16 + c];
          float x1 = acc[zz][mi][h2][r];
          float x2 = acc[zz][mi][h2 + 2][r];
          Ep[(rowb + r) * 72 + h2 * 16 + c]       = f2b((x1 * cs + x2 * sn) * scl);
          Ep[(rowb + r) * 72 + (h2 + 2) * 16 + c] = f2b((x2 * cs - x1 * sn) * scl);
        }
      }
    }
    __syncthreads();
    {
      int row = tid >> 1, half = tid & 1;
      int t = tbase + row;
      u16* Og = (zz == 0) ? Qo : Ko;
      u16* dst = Og + (((size_t)(bb2 * H_ + hh)) * T_ + t) * D_ + half * 32;
#pragma unroll
      for (int i = 0; i < 4; i++)
        *reinterpret_cast<uint4*>(dst + i * 8) =
            *reinterpret_cast<const uint4*>(Ep + row * 72 + half * 32 + i * 8);
    }
  }
}

// ---------------------------------------------------------------------------
// MFMA flash attention — round-3 version verbatim (best measured: 95 us).
// LDS double-buffer, one barrier/tile, R3 swizzle, XCD remap, setprio.
// ---------------------------------------------------------------------------
__global__ __launch_bounds__(256, 3) void attn_mfma(
    const u16* __restrict__ Qg, const u16* __restrict__ Kg,
    const u16* __restrict__ Vtg, u16* __restrict__ Yg)
{
  // two buffers: buf b at smem + b*8192: Ks[4096] | Vs[4096] u16 (32 KB total)
  __shared__ __align__(16) u16 smem[16384];

  const int tid = threadIdx.x;
  const int w = tid >> 6;
  const int lane = tid & 63;
  const int hi = lane >> 5;
  const int lq = lane & 31;

  // XCD remap: 768 wgs = 8 xcds x (6 bh x 16 q-blocks)
  const int id = blockIdx.x;
  const int xcd = id & 7;
  const int slot = id >> 3;              // 0..95
  const int bh = xcd * 6 + (slot >> 4);  // 0..47
  const int q0 = (slot & 15) * 128;

  const size_t baseQK = (size_t)bh * T_ * D_;
  const size_t baseV  = (size_t)bh * D_ * T_;

  // Q fragments (B-operand): lane holds Q[q0+w*32+lq][ds*16 + hi*8 + j]
  short8 qf[4];
  {
    const u16* qp = Qg + baseQK + (size_t)(q0 + w * 32 + lq) * D_ + hi * 8;
#pragma unroll
    for (int d = 0; d < 4; d++)
      qf[d] = *reinterpret_cast<const short8*>(qp + d * 16);
  }

  floatx16 z16;
#pragma unroll
  for (int i = 0; i < 16; i++) z16[i] = 0.f;
  short8 vones;
#pragma unroll
  for (int i = 0; i < 8; i++) vones[i] = (short)0x3F80;

  // staging: 256 threads cover 64 rows x 2 x 16B chunks; R3 slot swizzle
  const int sr = tid >> 2;
  const int sch = tid & 3;
  const int r3s = ((sr & 3) << 1) | ((sr >> 2) & 1);   // R3(sr&7)
  const int ko0 = sr * 64 + ((sch ^ r3s) * 8);
  const int ko1 = sr * 64 + (((sch + 4) ^ r3s) * 8);
  const int vo0 = 4096 + ko0;
  const int vo1 = 4096 + ko1;
  const u16* kga = Kg + baseQK + (size_t)sr * D_ + sch * 8;
  const u16* vga = Vtg + baseV + (size_t)sr * T_ + sch * 8;

  // prologue: tile 0 -> regs -> buf0; then prefetch tile 1 into regs
  uint4 ka = *reinterpret_cast<const uint4*>(kga);
  uint4 kb = *reinterpret_cast<const uint4*>(kga + 32);
  uint4 va = *reinterpret_cast<const uint4*>(vga);
  uint4 vb = *reinterpret_cast<const uint4*>(vga + 32);
  *reinterpret_cast<uint4*>(smem + ko0) = ka;
  *reinterpret_cast<uint4*>(smem + ko1) = kb;
  *reinterpret_cast<uint4*>(smem + vo0) = va;
  *reinterpret_cast<uint4*>(smem + vo1) = vb;
  const u16* kload = kga + (size_t)64 * D_;
  const u16* vload = vga + 64;
  ka = *reinterpret_cast<const uint4*>(kload);
  kb = *reinterpret_cast<const uint4*>(kload + 32);
  va = *reinterpret_cast<const uint4*>(vload);
  vb = *reinterpret_cast<const uint4*>(vload + 32);
  kload += (size_t)64 * D_;
  vload += 64;

  floatx16 o0 = z16, o1 = z16;
  floatx16 l_acc = z16;

  const int r3q = ((lq & 3) << 1) | ((lq >> 2) & 1);   // R3(lq&7)

  for (int kt = 0; kt < 32; kt++) {
    __syncthreads();   // buf[kt&1] fully written; buf[(kt+1)&1] fully read

    // write prefetched tile kt+1 into the other buffer; issue loads kt+2
    if (kt < 31) {
      u16* wb = smem + (((kt + 1) & 1) << 13);
      *reinterpret_cast<uint4*>(wb + ko0) = ka;
      *reinterpret_cast<uint4*>(wb + ko1) = kb;
      *reinterpret_cast<uint4*>(wb + vo0) = va;
      *reinterpret_cast<uint4*>(wb + vo1) = vb;
      if (kt < 30) {
        ka = *reinterpret_cast<const uint4*>(kload);
        kb = *reinterpret_cast<const uint4*>(kload + 32);
        va = *reinterpret_cast<const uint4*>(vload);
        vb = *reinterpret_cast<const uint4*>(vload + 32);
        kload += (size_t)64 * D_;
        vload += 64;
      }
    }

    const u16* Ksb = smem + ((kt & 1) << 13);
    const u16* Vsb = Ksb + 4096;

    // ---- QK^T (swapped): st = K * Q^T, col = q (lane-local), rows = t ----
    floatx16 st0, st1;
    __builtin_amdgcn_s_setprio(1);
    {
      const int xr = hi ^ r3q;
      short8 kf0 = *reinterpret_cast<const short8*>(Ksb + lq * 64 + xr * 8);
      short8 kf1 = *reinterpret_cast<const short8*>(Ksb + (32 + lq) * 64 + xr * 8);
      st0 = __builtin_amdgcn_mfma_f32_32x32x16_bf16(kf0, qf[0], z16, 0, 0, 0);
      st1 = __builtin_amdgcn_mfma_f32_32x32x16_bf16(kf1, qf[0], z16, 0, 0, 0);
    }
#pragma unroll
    for (int ds = 1; ds < 4; ds++) {
      const int xr = (ds * 2 + hi) ^ r3q;
      short8 kf0 = *reinterpret_cast<const short8*>(Ksb + lq * 64 + xr * 8);
      short8 kf1 = *reinterpret_cast<const short8*>(Ksb + (32 + lq) * 64 + xr * 8);
      st0 = __builtin_amdgcn_mfma_f32_32x32x16_bf16(kf0, qf[ds], st0, 0, 0, 0);
      st1 = __builtin_amdgcn_mfma_f32_32x32x16_bf16(kf1, qf[ds], st1, 0, 0, 0);
    }
    __builtin_amdgcn_s_setprio(0);

    // ---- softmax: p = exp2(s)  (scale folded into Q, bias cancels) ----
#pragma unroll
    for (int r = 0; r < 16; r++) {
      st0[r] = exp2f(st0[r]);
      st1[r] = exp2f(st1[r]);
    }

    // ---- P -> bf16 A-fragments: 16 cvt_pk + 8 permlane32_swap ----
    short8 pa[4];
#pragma unroll
    for (int ks = 0; ks < 4; ks++) {
      const floatx16& s = (ks < 2) ? st0 : st1;
      const int rb = (ks & 1) * 8;
      u32 ca = pack_bf16(s[rb + 0], s[rb + 1]);
      u32 cb = pack_bf16(s[rb + 2], s[rb + 3]);
      u32 cc = pack_bf16(s[rb + 4], s[rb + 5]);
      u32 cd = pack_bf16(s[rb + 6], s[rb + 7]);
      plswap(ca, cc);
      plswap(cb, cd);
      short8 pf;
      u32* pfu = reinterpret_cast<u32*>(&pf);
      pfu[0] = ca; pfu[1] = cb; pfu[2] = cc; pfu[3] = cd;
      pa[ks] = pf;
    }

    // ---- PV + l row-sums ----
    __builtin_amdgcn_s_setprio(1);
#pragma unroll
    for (int nt = 0; nt < 2; nt++) {
      const int d = nt * 32 + lq;
      floatx16& o = nt ? o1 : o0;
#pragma unroll
      for (int ks = 0; ks < 4; ks++) {
        short8 vf = *reinterpret_cast<const short8*>(
            Vsb + d * 64 + (((ks * 2 + hi) ^ r3q) * 8));
        o = __builtin_amdgcn_mfma_f32_32x32x16_bf16(pa[ks], vf, o, 0, 0, 0);
      }
    }
#pragma unroll
    for (int ks = 0; ks < 4; ks++)
      l_acc = __builtin_amdgcn_mfma_f32_32x32x16_bf16(pa[ks], vones, l_acc, 0, 0, 0);
    __builtin_amdgcn_s_setprio(0);
  }

  // normalization: l_acc[r] holds l for exactly the q-row o[r] holds
  float invr[16];
#pragma unroll
  for (int r = 0; r < 16; r++) invr[r] = __builtin_amdgcn_rcpf(l_acc[r]);

  __syncthreads();   // done with K/V buffers; reuse smem for epilogue
  u16* Ep = smem + w * (32 * 72);
#pragma unroll
  for (int nt = 0; nt < 2; nt++) {
    const floatx16& o = nt ? o1 : o0;
#pragma unroll
    for (int r = 0; r < 16; r++) {
      const int rl = (r & 3) + 8 * (r >> 2) + 4 * hi;
      Ep[rl * 72 + nt * 32 + lq] = f2b(o[r] * invr[r]);
    }
  }
  __syncthreads();
  {
    const int row = tid >> 1, half = tid & 1;   // 128 rows x 2 halves of 64B
    const u16* src = smem + (row >> 5) * (32 * 72) + (row & 31) * 72 + half * 32;
    const int t = q0 + row;
    const int b = bh / H_, h = bh % H_;
    const size_t yi = ((size_t)b * T_ + t) * C_ + (size_t)h * 64 + half * 32;
#pragma unroll
    for (int i = 0; i < 4; i++)
      *reinterpret_cast<uint4*>(Yg + yi + i * 8) =
          *reinterpret_cast<const uint4*>(src + i * 8);
  }
}

// ---------------------------------------------------------------------------
// Out projection — round 5: bf16 W (from prep), global_load_lds staging,
// linear LDS layout.  XCD remap unchanged.
// ---------------------------------------------------------------------------
__global__ __launch_bounds__(256) void out_mfma(
    const u16* __restrict__ Xb, const u16* __restrict__ Wfb, float* __restrict__ Og)
{
  __shared__ __align__(16) u16 smem[17408];   // As|Bs (24 KB), then fp32 Ep (34816 B)
  u16* As = smem;
  u16* Bs = smem + 128 * 64;

  const int id = blockIdx.x;
  const int xcd = id & 7;
  const int s = id >> 3;              // 0..95
  const int m0 = (xcd * 16 + s / 6) * 128;
  const int n0 = (s % 6) * 64;

  const int tid = threadIdx.x;
  const int w = tid >> 6;
  const int lane = tid & 63;
  const int quad = lane >> 4;
  const int c = lane & 15;

  floatx4 acc[2][4];
#pragma unroll
  for (int i = 0; i < 2; i++)
#pragma unroll
    for (int j = 0; j < 4; j++) acc[i][j] = (floatx4){0.f, 0.f, 0.f, 0.f};

  const int lrow = lane >> 3;
  const int lcol = (lane & 7) * 8;

  for (int k0 = 0; k0 < 384; k0 += 64) {
    __syncthreads();
#pragma unroll
    for (int n = 0; n < 4; n++) {
      const int ch = w * 4 + n;
      gl_lds16(Xb + (size_t)(m0 + ch * 8 + lrow) * C_ + k0 + lcol, As + ch * 512);
    }
#pragma unroll
    for (int n = 0; n < 2; n++) {
      const int ch = w * 2 + n;
      gl_lds16(Wfb + (size_t)(n0 + ch * 8 + lrow) * C_ + k0 + lcol, Bs + ch * 512);
    }
    __syncthreads();

#pragma unroll
    for (int ks = 0; ks < 2; ks++) {
      short8 af[2], bf[4];
#pragma unroll
      for (int mi = 0; mi < 2; mi++)
        af[mi] = *reinterpret_cast<const short8*>(
            As + (w * 32 + mi * 16 + c) * 64 + (ks * 4 + quad) * 8);
#pragma unroll
      for (int ni = 0; ni < 4; ni++)
        bf[ni] = *reinterpret_cast<const short8*>(
            Bs + (ni * 16 + c) * 64 + (ks * 4 + quad) * 8);
#pragma unroll
      for (int mi = 0; mi < 2; mi++)
#pragma unroll
        for (int ni = 0; ni < 4; ni++)
          acc[mi][ni] = __builtin_amdgcn_mfma_f32_16x16x32_bf16(af[mi], bf[ni], acc[mi][ni], 0, 0, 0);
    }
  }

  __syncthreads();
  float* Ep = reinterpret_cast<float*>(smem) + w * (32 * 68);
#pragma unroll
  for (int mi = 0; mi < 2; mi++)
#pragma unroll
    for (int ni = 0; ni < 4; ni++) {
      int rw = mi * 16 + quad * 4;
      int col = ni * 16 + c;
#pragma unroll
      for (int r = 0; r < 4; r++)
        Ep[(rw + r) * 68 + col] = acc[mi][ni][r];
    }
  __syncthreads();
  {
    int rw2 = lane >> 1, half = lane & 1;
    const float* src = Ep + rw2 * 68 + half * 32;
    float* dst = Og + (size_t)(m0 + w * 32 + rw2) * C_ + n0 + half * 32;
#pragma unroll
    for (int i = 0; i < 8; i++)
      *reinterpret_cast<float4*>(dst + i * 4) =
          *reinterpret_cast<const float4*>(src + i * 4);
  }
}

// ---------------------------------------------------------------------------
extern "C" void kernel_launch(void* const* d_in, const int* in_sizes, int n_in,
                              void* d_out, int out_size, void* d_ws, size_t ws_size,
                              hipStream_t stream) {
  (void)in_sizes; (void)n_in; (void)out_size; (void)ws_size;
  const float* x    = (const float*)d_in[0];
  const float* Wq   = (const float*)d_in[1];
  const float* Wk   = (const float*)d_in[2];
  const float* Wv   = (const float*)d_in[3];
  const float* Wo   = (const float*)d_in[4];
  const float* cosb = (const float*)d_in[5];
  const float* sinb = (const float*)d_in[6];

  const size_t MC = (size_t)M_ * C_;    // 6291456
  u16* ws = (u16*)d_ws;
  u16* Q   = ws;                        // [B][H][T][D] bf16 (pre-scaled)
  u16* K   = Q + MC;
  u16* Vt  = K + MC;                    // [B][H][D][T] bf16
  u16* Y   = Vt + MC;                   // attn out [B*T][C] bf16; doubles as Xb
  u16* Xb  = Y;                         // bf16 X (consumed by qkv before attn writes Y)
  u16* Wb  = Y + MC;                    // 4 x 147456 bf16 weights
  u16* Wqb = Wb;
  u16* Wkb = Wb + 147456;
  u16* Wvb = Wb + 2 * 147456;
  u16* Wob = Wb + 3 * 147456;
  float* out = (float*)d_out;

  prep_bf16<<<3360, 256, 0, stream>>>(x, Wq, Wk, Wv, Wo, Xb, Wqb, Wkb, Wvb, Wob);

  qkv_fused<<<768, 256, 0, stream>>>(Xb, Wqb, Wkb, Wvb, cosb, sinb, Q, K, Vt);

  attn_mfma<<<768, 256, 0, stream>>>(Q, K, Vt, Y);

  out_mfma<<<768, 256, 0, stream>>>(Y, Wob, out);
}

// Round 6
// 213.958 us; speedup vs baseline: 1.6130x; 1.1177x over previous
//
#include <hip/hip_runtime.h>
#include <hip/hip_bf16.h>
#include <stdint.h>

#define B_ 8
#define T_ 2048
#define C_ 384
#define H_ 6
#define D_ 64
#define M_ (B_*T_)   // 16384

typedef unsigned short u16;
typedef unsigned int u32;
typedef __attribute__((ext_vector_type(8))) short short8;
typedef __attribute__((ext_vector_type(4))) float floatx4;
typedef __attribute__((ext_vector_type(16))) float floatx16;

// softmax scale folded into stored Q: 0.125 * log2(e)
#define QSCALE 0.18033688011112042f

__device__ __forceinline__ u16 f2b(float f) {
  union { float f; unsigned u; } x; x.f = f;
  unsigned r = x.u + 0x7fffu + ((x.u >> 16) & 1u);  // round-nearest-even
  return (u16)(r >> 16);
}
__device__ __forceinline__ u32 pack_bf16(float a, float b) {
  union { __hip_bfloat162 h; u32 u; } x;
  x.h = __float22bfloat162_rn(float2{a, b});
  return x.u;
}
__device__ __forceinline__ uint4 pack8(const float4& lo, const float4& hi) {
  uint4 r;
  r.x = pack_bf16(lo.x, lo.y); r.y = pack_bf16(lo.z, lo.w);
  r.z = pack_bf16(hi.x, hi.y); r.w = pack_bf16(hi.z, hi.w);
  return r;
}

// v_permlane32_swap_b32: swaps a.hi(32 lanes) <-> b.lo(32 lanes).
__device__ __forceinline__ void plswap(u32& a, u32& b) {
  asm("v_permlane32_swap_b32 %0, %1" : "+v"(a), "+v"(b));
}

// bare v_exp_f32 — no libm range/denormal fixup (inputs bounded: |s|<=11.6)
__device__ __forceinline__ float fexp2(float x) {
#if __has_builtin(__builtin_amdgcn_exp2f)
  return __builtin_amdgcn_exp2f(x);
#else
  float r; asm("v_exp_f32 %0, %1" : "=v"(r) : "v"(x)); return r;
#endif
}

// packed f32x2 -> bf16x2 in ONE instruction (dst.lo = bf16(a), dst.hi = bf16(b))
__device__ __forceinline__ u32 cvtpk(float a, float b) {
  u32 r; asm("v_cvt_pk_bf16_f32 %0, %1, %2" : "=v"(r) : "v"(a), "v"(b)); return r;
}

// async global->LDS, 16B per lane.
__device__ __forceinline__ void gl_lds16(const u16* g, u16* l) {
#if __has_builtin(__builtin_amdgcn_global_load_lds)
  __builtin_amdgcn_global_load_lds(
      (const __attribute__((address_space(1))) unsigned int*)g,
      (__attribute__((address_space(3))) unsigned int*)l,
      16, 0, 0);
#else
  *reinterpret_cast<uint4*>(l + (threadIdx.x & 63) * 8) =
      *reinterpret_cast<const uint4*>(g);
#endif
}

// ---------------------------------------------------------------------------
// prep: one-time fp32 -> bf16 conversion of X and the four weight matrices.
// ---------------------------------------------------------------------------
__global__ __launch_bounds__(256) void prep_bf16(
    const float* __restrict__ x,
    const float* __restrict__ wq, const float* __restrict__ wk,
    const float* __restrict__ wv, const float* __restrict__ wo,
    u16* __restrict__ xb,
    u16* __restrict__ wqb, u16* __restrict__ wkb,
    u16* __restrict__ wvb, u16* __restrict__ wob)
{
  const int c = blockIdx.x * 256 + threadIdx.x;
  const float* src;
  u16* dst;
  int off;
  if (c < 786432) {                 // X: 6291456 / 8
    src = x; dst = xb; off = c;
  } else {
    int t = c - 786432;             // W: 147456 / 8 = 18432 chunks each
    int wsel = t / 18432;
    off = t - wsel * 18432;
    src = (wsel == 0) ? wq : (wsel == 1) ? wk : (wsel == 2) ? wv : wo;
    dst = (wsel == 0) ? wqb : (wsel == 1) ? wkb : (wsel == 2) ? wvb : wob;
  }
  const float4* p = reinterpret_cast<const float4*>(src + (size_t)off * 8);
  float4 lo = p[0], hi = p[1];
  *reinterpret_cast<uint4*>(dst + (size_t)off * 8) = pack8(lo, hi);
}

// ---------------------------------------------------------------------------
// Fused QKV projection — bf16 operands, global_load_lds staging (round 5).
// ---------------------------------------------------------------------------
__global__ __launch_bounds__(256) void qkv_fused(
    const u16* __restrict__ Xb,
    const u16* __restrict__ Wqb, const u16* __restrict__ Wkb, const u16* __restrict__ Wvb,
    const float* __restrict__ cosb, const float* __restrict__ sinb,
    u16* __restrict__ Qo, u16* __restrict__ Ko, u16* __restrict__ Vto)
{
  __shared__ __align__(16) u16 smem[128 * 64 + 3 * 64 * 64];  // As | Bs[3] (40 KB)
  u16* As = smem;
  u16* Bs0 = smem + 128 * 64;

  // XCD remap: 768 wgs = 8 xcds x (16 m-blocks x 6 heads)
  const int id = blockIdx.x;
  const int xcd = id & 7;
  const int s = id >> 3;              // 0..95
  const int mb = xcd * 16 + s / 6;    // 0..127
  const int hh = s % 6;
  const int m0 = mb * 128;
  const int n0 = hh * 64;

  const int tid = threadIdx.x;
  const int w = tid >> 6;
  const int lane = tid & 63;
  const int quad = lane >> 4;
  const int c = lane & 15;

  const u16* Wz[3] = {Wqb, Wkb, Wvb};

  floatx4 acc[3][2][4];
#pragma unroll
  for (int z = 0; z < 3; z++)
#pragma unroll
    for (int i = 0; i < 2; i++)
#pragma unroll
      for (int j = 0; j < 4; j++) acc[z][i][j] = (floatx4){0.f, 0.f, 0.f, 0.f};

  const int lrow = lane >> 3;        // row within an 8-row chunk
  const int lcol = (lane & 7) * 8;   // 8-col (16B) offset

  for (int k0 = 0; k0 < 384; k0 += 64) {
    __syncthreads();   // prior MFMA reads complete before overwrite
#pragma unroll
    for (int n = 0; n < 4; n++) {
      const int ch = w * 4 + n;
      gl_lds16(Xb + (size_t)(m0 + ch * 8 + lrow) * C_ + k0 + lcol, As + ch * 512);
    }
#pragma unroll
    for (int z = 0; z < 3; z++)
#pragma unroll
      for (int n = 0; n < 2; n++) {
        const int ch = w * 2 + n;
        gl_lds16(Wz[z] + (size_t)(n0 + ch * 8 + lrow) * C_ + k0 + lcol,
                 Bs0 + z * 4096 + ch * 512);
      }
    __syncthreads();   // implicit vmcnt(0) drain -> LDS ready

#pragma unroll
    for (int ks = 0; ks < 2; ks++) {
      short8 af2[2];
#pragma unroll
      for (int mi = 0; mi < 2; mi++)
        af2[mi] = *reinterpret_cast<const short8*>(
            As + (w * 32 + mi * 16 + c) * 64 + (ks * 4 + quad) * 8);
#pragma unroll
      for (int z = 0; z < 3; z++) {
#pragma unroll
        for (int ni = 0; ni < 4; ni++) {
          short8 bf = *reinterpret_cast<const short8*>(
              Bs0 + z * 4096 + (ni * 16 + c) * 64 + (ks * 4 + quad) * 8);
#pragma unroll
          for (int mi = 0; mi < 2; mi++)
            acc[z][mi][ni] = __builtin_amdgcn_mfma_f32_16x16x32_bf16(af2[mi], bf, acc[z][mi][ni], 0, 0, 0);
        }
      }
    }
  }

  const int bb2 = m0 >> 11;
  const int tbase = m0 & (T_ - 1);

  // ---- V: register scatter to Vt[B][H][D][T] ----
  {
    const size_t vbase = ((size_t)(bb2 * H_ + hh)) * D_ * T_;
#pragma unroll
    for (int mi = 0; mi < 2; mi++) {
      int t = tbase + w * 32 + mi * 16 + quad * 4;
#pragma unroll
      for (int ni = 0; ni < 4; ni++) {
        int d = ni * 16 + c;
        ushort4 pk;
        pk.x = f2b(acc[2][mi][ni][0]); pk.y = f2b(acc[2][mi][ni][1]);
        pk.z = f2b(acc[2][mi][ni][2]); pk.w = f2b(acc[2][mi][ni][3]);
        *reinterpret_cast<ushort4*>(Vto + vbase + (size_t)d * T_ + t) = pk;
      }
    }
  }

  // ---- Q then K: lane-parallel RMS + RoPE, LDS transpose store ----
  u16* Ep = smem;
#pragma unroll
  for (int zz = 0; zz < 2; zz++) {
    __syncthreads();
#pragma unroll
    for (int mi = 0; mi < 2; mi++) {
      float ssr[4];
#pragma unroll
      for (int r = 0; r < 4; r++) {
        float s0 = acc[zz][mi][0][r], s1 = acc[zz][mi][1][r];
        float s2 = acc[zz][mi][2][r], s3 = acc[zz][mi][3][r];
        ssr[r] = s0 * s0 + s1 * s1 + s2 * s2 + s3 * s3;
      }
#pragma unroll
      for (int off = 1; off < 16; off <<= 1)
#pragma unroll
        for (int r = 0; r < 4; r++) ssr[r] += __shfl_xor(ssr[r], off, 64);
      int rowb = w * 32 + mi * 16 + quad * 4;
#pragma unroll
      for (int r = 0; r < 4; r++) {
        float scl = rsqrtf(ssr[r] * (1.0f / 64.0f) + 1e-5f);
        if (zz == 0) scl *= QSCALE;     // fold softmax scale into Q
        int t = tbase + rowb + r;
#pragma unroll
        for (int h2 = 0; h2 < 2; h2++) {
          float cs = cosb[t * 32 + h2 * 16 + c];
          float sn = sinb[t * 32 + h2 * 16 + c];
          float x1 = acc[zz][mi][h2][r];
          float x2 = acc[zz][mi][h2 + 2][r];
          Ep[(rowb + r) * 72 + h2 * 16 + c]       = f2b((x1 * cs + x2 * sn) * scl);
          Ep[(rowb + r) * 72 + (h2 + 2) * 16 + c] = f2b((x2 * cs - x1 * sn) * scl);
        }
      }
    }
    __syncthreads();
    {
      int row = tid >> 1, half = tid & 1;
      int t = tbase + row;
      u16* Og = (zz == 0) ? Qo : Ko;
      u16* dst = Og + (((size_t)(bb2 * H_ + hh)) * T_ + t) * D_ + half * 32;
#pragma unroll
      for (int i = 0; i < 4; i++)
        *reinterpret_cast<uint4*>(dst + i * 8) =
            *reinterpret_cast<const uint4*>(Ep + row * 72 + half * 32 + i * 8);
    }
  }
}

// ---------------------------------------------------------------------------
// MFMA flash attention — round 6: round-3 structure + VALU diet:
// bare v_exp_f32 (no libm fixup), asm v_cvt_pk_bf16_f32 for P->bf16,
// hoisted thread-invariant LDS read offsets.
// ---------------------------------------------------------------------------
__global__ __launch_bounds__(256, 3) void attn_mfma(
    const u16* __restrict__ Qg, const u16* __restrict__ Kg,
    const u16* __restrict__ Vtg, u16* __restrict__ Yg)
{
  // two buffers: buf b at smem + b*8192: Ks[4096] | Vs[4096] u16 (32 KB total)
  __shared__ __align__(16) u16 smem[16384];

  const int tid = threadIdx.x;
  const int w = tid >> 6;
  const int lane = tid & 63;
  const int hi = lane >> 5;
  const int lq = lane & 31;

  // XCD remap: 768 wgs = 8 xcds x (6 bh x 16 q-blocks)
  const int id = blockIdx.x;
  const int xcd = id & 7;
  const int slot = id >> 3;              // 0..95
  const int bh = xcd * 6 + (slot >> 4);  // 0..47
  const int q0 = (slot & 15) * 128;

  const size_t baseQK = (size_t)bh * T_ * D_;
  const size_t baseV  = (size_t)bh * D_ * T_;

  // Q fragments (B-operand): lane holds Q[q0+w*32+lq][ds*16 + hi*8 + j]
  short8 qf[4];
  {
    const u16* qp = Qg + baseQK + (size_t)(q0 + w * 32 + lq) * D_ + hi * 8;
#pragma unroll
    for (int d = 0; d < 4; d++)
      qf[d] = *reinterpret_cast<const short8*>(qp + d * 16);
  }

  floatx16 z16;
#pragma unroll
  for (int i = 0; i < 16; i++) z16[i] = 0.f;
  short8 vones;
#pragma unroll
  for (int i = 0; i < 8; i++) vones[i] = (short)0x3F80;

  // staging: 256 threads cover 64 rows x 2 x 16B chunks; R3 slot swizzle
  const int sr = tid >> 2;
  const int sch = tid & 3;
  const int r3s = ((sr & 3) << 1) | ((sr >> 2) & 1);   // R3(sr&7)
  const int ko0 = sr * 64 + ((sch ^ r3s) * 8);
  const int ko1 = sr * 64 + (((sch + 4) ^ r3s) * 8);
  const int vo0 = 4096 + ko0;
  const int vo1 = 4096 + ko1;
  const u16* kga = Kg + baseQK + (size_t)sr * D_ + sch * 8;
  const u16* vga = Vtg + baseV + (size_t)sr * T_ + sch * 8;

  // prologue: tile 0 -> regs -> buf0; then prefetch tile 1 into regs
  uint4 ka = *reinterpret_cast<const uint4*>(kga);
  uint4 kb = *reinterpret_cast<const uint4*>(kga + 32);
  uint4 va = *reinterpret_cast<const uint4*>(vga);
  uint4 vb = *reinterpret_cast<const uint4*>(vga + 32);
  *reinterpret_cast<uint4*>(smem + ko0) = ka;
  *reinterpret_cast<uint4*>(smem + ko1) = kb;
  *reinterpret_cast<uint4*>(smem + vo0) = va;
  *reinterpret_cast<uint4*>(smem + vo1) = vb;
  const u16* kload = kga + (size_t)64 * D_;
  const u16* vload = vga + 64;
  ka = *reinterpret_cast<const uint4*>(kload);
  kb = *reinterpret_cast<const uint4*>(kload + 32);
  va = *reinterpret_cast<const uint4*>(vload);
  vb = *reinterpret_cast<const uint4*>(vload + 32);
  kload += (size_t)64 * D_;
  vload += 64;

  floatx16 o0 = z16, o1 = z16;
  floatx16 l_acc = z16;

  const int r3q = ((lq & 3) << 1) | ((lq >> 2) & 1);   // R3(lq&7)

  // hoisted thread-invariant LDS read offsets (u16 indices into a buffer)
  int koff[2][4], voff[2][4];
#pragma unroll
  for (int ds = 0; ds < 4; ds++) {
    const int xr = (ds * 2 + hi) ^ r3q;
    koff[0][ds] = lq * 64 + xr * 8;
    koff[1][ds] = (32 + lq) * 64 + xr * 8;
    voff[0][ds] = 4096 + lq * 64 + xr * 8;
    voff[1][ds] = 4096 + (32 + lq) * 64 + xr * 8;
  }

  for (int kt = 0; kt < 32; kt++) {
    __syncthreads();   // buf[kt&1] fully written; buf[(kt+1)&1] fully read

    // write prefetched tile kt+1 into the other buffer; issue loads kt+2
    if (kt < 31) {
      u16* wb = smem + (((kt + 1) & 1) << 13);
      *reinterpret_cast<uint4*>(wb + ko0) = ka;
      *reinterpret_cast<uint4*>(wb + ko1) = kb;
      *reinterpret_cast<uint4*>(wb + vo0) = va;
      *reinterpret_cast<uint4*>(wb + vo1) = vb;
      if (kt < 30) {
        ka = *reinterpret_cast<const uint4*>(kload);
        kb = *reinterpret_cast<const uint4*>(kload + 32);
        va = *reinterpret_cast<const uint4*>(vload);
        vb = *reinterpret_cast<const uint4*>(vload + 32);
        kload += (size_t)64 * D_;
        vload += 64;
      }
    }

    const u16* Ksb = smem + ((kt & 1) << 13);

    // ---- QK^T (swapped): st = K * Q^T, col = q (lane-local), rows = t ----
    floatx16 st0, st1;
    __builtin_amdgcn_s_setprio(1);
    {
      short8 kf0 = *reinterpret_cast<const short8*>(Ksb + koff[0][0]);
      short8 kf1 = *reinterpret_cast<const short8*>(Ksb + koff[1][0]);
      st0 = __builtin_amdgcn_mfma_f32_32x32x16_bf16(kf0, qf[0], z16, 0, 0, 0);
      st1 = __builtin_amdgcn_mfma_f32_32x32x16_bf16(kf1, qf[0], z16, 0, 0, 0);
    }
#pragma unroll
    for (int ds = 1; ds < 4; ds++) {
      short8 kf0 = *reinterpret_cast<const short8*>(Ksb + koff[0][ds]);
      short8 kf1 = *reinterpret_cast<const short8*>(Ksb + koff[1][ds]);
      st0 = __builtin_amdgcn_mfma_f32_32x32x16_bf16(kf0, qf[ds], st0, 0, 0, 0);
      st1 = __builtin_amdgcn_mfma_f32_32x32x16_bf16(kf1, qf[ds], st1, 0, 0, 0);
    }
    __builtin_amdgcn_s_setprio(0);

    // ---- softmax: p = exp2(s), bare v_exp_f32 ----
#pragma unroll
    for (int r = 0; r < 16; r++) {
      st0[r] = fexp2(st0[r]);
      st1[r] = fexp2(st1[r]);
    }

    // ---- P -> bf16 A-fragments: 16 v_cvt_pk + 8 permlane32_swap ----
    short8 pa[4];
#pragma unroll
    for (int ks = 0; ks < 4; ks++) {
      const floatx16& s = (ks < 2) ? st0 : st1;
      const int rb = (ks & 1) * 8;
      u32 ca = cvtpk(s[rb + 0], s[rb + 1]);
      u32 cb = cvtpk(s[rb + 2], s[rb + 3]);
      u32 cc = cvtpk(s[rb + 4], s[rb + 5]);
      u32 cd = cvtpk(s[rb + 6], s[rb + 7]);
      plswap(ca, cc);
      plswap(cb, cd);
      short8 pf;
      u32* pfu = reinterpret_cast<u32*>(&pf);
      pfu[0] = ca; pfu[1] = cb; pfu[2] = cc; pfu[3] = cd;
      pa[ks] = pf;
    }

    // ---- PV + l row-sums ----
    __builtin_amdgcn_s_setprio(1);
#pragma unroll
    for (int ks = 0; ks < 4; ks++) {
      short8 vf0 = *reinterpret_cast<const short8*>(Ksb + voff[0][ks]);
      short8 vf1 = *reinterpret_cast<const short8*>(Ksb + voff[1][ks]);
      o0 = __builtin_amdgcn_mfma_f32_32x32x16_bf16(pa[ks], vf0, o0, 0, 0, 0);
      o1 = __builtin_amdgcn_mfma_f32_32x32x16_bf16(pa[ks], vf1, o1, 0, 0, 0);
    }
#pragma unroll
    for (int ks = 0; ks < 4; ks++)
      l_acc = __builtin_amdgcn_mfma_f32_32x32x16_bf16(pa[ks], vones, l_acc, 0, 0, 0);
    __builtin_amdgcn_s_setprio(0);
  }

  // normalization: l_acc[r] holds l for exactly the q-row o[r] holds
  float invr[16];
#pragma unroll
  for (int r = 0; r < 16; r++) invr[r] = __builtin_amdgcn_rcpf(l_acc[r]);

  __syncthreads();   // done with K/V buffers; reuse smem for epilogue
  u16* Ep = smem + w * (32 * 72);
#pragma unroll
  for (int nt = 0; nt < 2; nt++) {
    const floatx16& o = nt ? o1 : o0;
#pragma unroll
    for (int r = 0; r < 16; r++) {
      const int rl = (r & 3) + 8 * (r >> 2) + 4 * hi;
      Ep[rl * 72 + nt * 32 + lq] = f2b(o[r] * invr[r]);
    }
  }
  __syncthreads();
  {
    const int row = tid >> 1, half = tid & 1;   // 128 rows x 2 halves of 64B
    const u16* src = smem + (row >> 5) * (32 * 72) + (row & 31) * 72 + half * 32;
    const int t = q0 + row;
    const int b = bh / H_, h = bh % H_;
    const size_t yi = ((size_t)b * T_ + t) * C_ + (size_t)h * 64 + half * 32;
#pragma unroll
    for (int i = 0; i < 4; i++)
      *reinterpret_cast<uint4*>(Yg + yi + i * 8) =
          *reinterpret_cast<const uint4*>(src + i * 8);
  }
}

// ---------------------------------------------------------------------------
// Out projection — bf16 W, global_load_lds staging (round 5).
// ---------------------------------------------------------------------------
__global__ __launch_bounds__(256) void out_mfma(
    const u16* __restrict__ Xb, const u16* __restrict__ Wfb, float* __restrict__ Og)
{
  __shared__ __align__(16) u16 smem[17408];   // As|Bs (24 KB), then fp32 Ep (34816 B)
  u16* As = smem;
  u16* Bs = smem + 128 * 64;

  const int id = blockIdx.x;
  const int xcd = id & 7;
  const int s = id >> 3;              // 0..95
  const int m0 = (xcd * 16 + s / 6) * 128;
  const int n0 = (s % 6) * 64;

  const int tid = threadIdx.x;
  const int w = tid >> 6;
  const int lane = tid & 63;
  const int quad = lane >> 4;
  const int c = lane & 15;

  floatx4 acc[2][4];
#pragma unroll
  for (int i = 0; i < 2; i++)
#pragma unroll
    for (int j = 0; j < 4; j++) acc[i][j] = (floatx4){0.f, 0.f, 0.f, 0.f};

  const int lrow = lane >> 3;
  const int lcol = (lane & 7) * 8;

  for (int k0 = 0; k0 < 384; k0 += 64) {
    __syncthreads();
#pragma unroll
    for (int n = 0; n < 4; n++) {
      const int ch = w * 4 + n;
      gl_lds16(Xb + (size_t)(m0 + ch * 8 + lrow) * C_ + k0 + lcol, As + ch * 512);
    }
#pragma unroll
    for (int n = 0; n < 2; n++) {
      const int ch = w * 2 + n;
      gl_lds16(Wfb + (size_t)(n0 + ch * 8 + lrow) * C_ + k0 + lcol, Bs + ch * 512);
    }
    __syncthreads();

#pragma unroll
    for (int ks = 0; ks < 2; ks++) {
      short8 af[2], bf[4];
#pragma unroll
      for (int mi = 0; mi < 2; mi++)
        af[mi] = *reinterpret_cast<const short8*>(
            As + (w * 32 + mi * 16 + c) * 64 + (ks * 4 + quad) * 8);
#pragma unroll
      for (int ni = 0; ni < 4; ni++)
        bf[ni] = *reinterpret_cast<const short8*>(
            Bs + (ni * 16 + c) * 64 + (ks * 4 + quad) * 8);
#pragma unroll
      for (int mi = 0; mi < 2; mi++)
#pragma unroll
        for (int ni = 0; ni < 4; ni++)
          acc[mi][ni] = __builtin_amdgcn_mfma_f32_16x16x32_bf16(af[mi], bf[ni], acc[mi][ni], 0, 0, 0);
    }
  }

  __syncthreads();
  float* Ep = reinterpret_cast<float*>(smem) + w * (32 * 68);
#pragma unroll
  for (int mi = 0; mi < 2; mi++)
#pragma unroll
    for (int ni = 0; ni < 4; ni++) {
      int rw = mi * 16 + quad * 4;
      int col = ni * 16 + c;
#pragma unroll
      for (int r = 0; r < 4; r++)
        Ep[(rw + r) * 68 + col] = acc[mi][ni][r];
    }
  __syncthreads();
  {
    int rw2 = lane >> 1, half = lane & 1;
    const float* src = Ep + rw2 * 68 + half * 32;
    float* dst = Og + (size_t)(m0 + w * 32 + rw2) * C_ + n0 + half * 32;
#pragma unroll
    for (int i = 0; i < 8; i++)
      *reinterpret_cast<float4*>(dst + i * 4) =
          *reinterpret_cast<const float4*>(src + i * 4);
  }
}

// ---------------------------------------------------------------------------
extern "C" void kernel_launch(void* const* d_in, const int* in_sizes, int n_in,
                              void* d_out, int out_size, void* d_ws, size_t ws_size,
                              hipStream_t stream) {
  (void)in_sizes; (void)n_in; (void)out_size; (void)ws_size;
  const float* x    = (const float*)d_in[0];
  const float* Wq   = (const float*)d_in[1];
  const float* Wk   = (const float*)d_in[2];
  const float* Wv   = (const float*)d_in[3];
  const float* Wo   = (const float*)d_in[4];
  const float* cosb = (const float*)d_in[5];
  const float* sinb = (const float*)d_in[6];

  const size_t MC = (size_t)M_ * C_;    // 6291456
  u16* ws = (u16*)d_ws;
  u16* Q   = ws;                        // [B][H][T][D] bf16 (pre-scaled)
  u16* K   = Q + MC;
  u16* Vt  = K + MC;                    // [B][H][D][T] bf16
  u16* Y   = Vt + MC;                   // attn out [B*T][C] bf16; doubles as Xb
  u16* Xb  = Y;                         // bf16 X (consumed by qkv before attn writes Y)
  u16* Wb  = Y + MC;                    // 4 x 147456 bf16 weights
  u16* Wqb = Wb;
  u16* Wkb = Wb + 147456;
  u16* Wvb = Wb + 2 * 147456;
  u16* Wob = Wb + 3 * 147456;
  float* out = (float*)d_out;

  prep_bf16<<<3360, 256, 0, stream>>>(x, Wq, Wk, Wv, Wo, Xb, Wqb, Wkb, Wvb, Wob);

  qkv_fused<<<768, 256, 0, stream>>>(Xb, Wqb, Wkb, Wvb, cosb, sinb, Q, K, Vt);

  attn_mfma<<<768, 256, 0, stream>>>(Q, K, Vt, Y);

  out_mfma<<<768, 256, 0, stream>>>(Y, Wob, out);
}

// Round 7
// 206.328 us; speedup vs baseline: 1.6726x; 1.0370x over previous
//
#include <hip/hip_runtime.h>
#include <hip/hip_bf16.h>
#include <stdint.h>

#define B_ 8
#define T_ 2048
#define C_ 384
#define H_ 6
#define D_ 64
#define M_ (B_*T_)   // 16384

typedef unsigned short u16;
typedef unsigned int u32;
typedef __attribute__((ext_vector_type(8))) short short8;
typedef __attribute__((ext_vector_type(4))) float floatx4;
typedef __attribute__((ext_vector_type(16))) float floatx16;

// softmax scale folded into stored Q: 0.125 * log2(e)
#define QSCALE 0.18033688011112042f

__device__ __forceinline__ u16 f2b(float f) {
  union { float f; unsigned u; } x; x.f = f;
  unsigned r = x.u + 0x7fffu + ((x.u >> 16) & 1u);  // round-nearest-even
  return (u16)(r >> 16);
}
__device__ __forceinline__ u32 pack_bf16(float a, float b) {
  union { __hip_bfloat162 h; u32 u; } x;
  x.h = __float22bfloat162_rn(float2{a, b});
  return x.u;
}
__device__ __forceinline__ uint4 pack8(const float4& lo, const float4& hi) {
  uint4 r;
  r.x = pack_bf16(lo.x, lo.y); r.y = pack_bf16(lo.z, lo.w);
  r.z = pack_bf16(hi.x, hi.y); r.w = pack_bf16(hi.z, hi.w);
  return r;
}

// v_permlane32_swap_b32: swaps a.hi(32 lanes) <-> b.lo(32 lanes).
__device__ __forceinline__ void plswap(u32& a, u32& b) {
  asm("v_permlane32_swap_b32 %0, %1" : "+v"(a), "+v"(b));
}

// bare v_exp_f32 — no libm range/denormal fixup (inputs bounded: |s|<=11.6)
__device__ __forceinline__ float fexp2(float x) {
#if __has_builtin(__builtin_amdgcn_exp2f)
  return __builtin_amdgcn_exp2f(x);
#else
  float r; asm("v_exp_f32 %0, %1" : "=v"(r) : "v"(x)); return r;
#endif
}

// packed f32x2 -> bf16x2 in ONE instruction (dst.lo = bf16(a), dst.hi = bf16(b))
__device__ __forceinline__ u32 cvtpk(float a, float b) {
  u32 r; asm("v_cvt_pk_bf16_f32 %0, %1, %2" : "=v"(r) : "v"(a), "v"(b)); return r;
}

// async global->LDS, 16B per lane.
__device__ __forceinline__ void gl_lds16(const u16* g, u16* l) {
#if __has_builtin(__builtin_amdgcn_global_load_lds)
  __builtin_amdgcn_global_load_lds(
      (const __attribute__((address_space(1))) unsigned int*)g,
      (__attribute__((address_space(3))) unsigned int*)l,
      16, 0, 0);
#else
  *reinterpret_cast<uint4*>(l + (threadIdx.x & 63) * 8) =
      *reinterpret_cast<const uint4*>(g);
#endif
}

// ---------------------------------------------------------------------------
// prep: one-time fp32 -> bf16 conversion of X and the four weight matrices.
// ---------------------------------------------------------------------------
__global__ __launch_bounds__(256) void prep_bf16(
    const float* __restrict__ x,
    const float* __restrict__ wq, const float* __restrict__ wk,
    const float* __restrict__ wv, const float* __restrict__ wo,
    u16* __restrict__ xb,
    u16* __restrict__ wqb, u16* __restrict__ wkb,
    u16* __restrict__ wvb, u16* __restrict__ wob)
{
  const int c = blockIdx.x * 256 + threadIdx.x;
  const float* src;
  u16* dst;
  int off;
  if (c < 786432) {                 // X: 6291456 / 8
    src = x; dst = xb; off = c;
  } else {
    int t = c - 786432;             // W: 147456 / 8 = 18432 chunks each
    int wsel = t / 18432;
    off = t - wsel * 18432;
    src = (wsel == 0) ? wq : (wsel == 1) ? wk : (wsel == 2) ? wv : wo;
    dst = (wsel == 0) ? wqb : (wsel == 1) ? wkb : (wsel == 2) ? wvb : wob;
  }
  const float4* p = reinterpret_cast<const float4*>(src + (size_t)off * 8);
  float4 lo = p[0], hi = p[1];
  *reinterpret_cast<uint4*>(dst + (size_t)off * 8) = pack8(lo, hi);
}

// ---------------------------------------------------------------------------
// Fused QKV projection — round 7: double-buffered LDS, STAGE(next) BEFORE
// compute(current), ONE barrier per k-step.  The compiler's vmcnt(0) drain
// before s_barrier now lands AFTER the MFMA work -> loads overlap compute.
// Per-buffer layout: As[128*64] | Bs[3][64*64]  (20480 u16); 2 buffers = 80 KB.
// ---------------------------------------------------------------------------
#define QKV_SBUF 20480

__global__ __launch_bounds__(256) void qkv_fused(
    const u16* __restrict__ Xb,
    const u16* __restrict__ Wqb, const u16* __restrict__ Wkb, const u16* __restrict__ Wvb,
    const float* __restrict__ cosb, const float* __restrict__ sinb,
    u16* __restrict__ Qo, u16* __restrict__ Ko, u16* __restrict__ Vto)
{
  __shared__ __align__(16) u16 smem[2 * QKV_SBUF];   // 80 KB

  // XCD remap: 768 wgs = 8 xcds x (16 m-blocks x 6 heads)
  const int id = blockIdx.x;
  const int xcd = id & 7;
  const int s = id >> 3;              // 0..95
  const int mb = xcd * 16 + s / 6;    // 0..127
  const int hh = s % 6;
  const int m0 = mb * 128;
  const int n0 = hh * 64;

  const int tid = threadIdx.x;
  const int w = tid >> 6;
  const int lane = tid & 63;
  const int quad = lane >> 4;
  const int c = lane & 15;

  const u16* Wz[3] = {Wqb, Wkb, Wvb};

  floatx4 acc[3][2][4];
#pragma unroll
  for (int z = 0; z < 3; z++)
#pragma unroll
    for (int i = 0; i < 2; i++)
#pragma unroll
      for (int j = 0; j < 4; j++) acc[z][i][j] = (floatx4){0.f, 0.f, 0.f, 0.f};

  const int lrow = lane >> 3;        // row within an 8-row chunk
  const int lcol = (lane & 7) * 8;   // 8-col (16B) offset

  // stage k-step k0 into buffer bb
  auto STAGE = [&](int bb, int k0) {
    u16* base = smem + bb * QKV_SBUF;
#pragma unroll
    for (int n = 0; n < 4; n++) {
      const int ch = w * 4 + n;
      gl_lds16(Xb + (size_t)(m0 + ch * 8 + lrow) * C_ + k0 + lcol, base + ch * 512);
    }
#pragma unroll
    for (int z = 0; z < 3; z++)
#pragma unroll
      for (int n = 0; n < 2; n++) {
        const int ch = w * 2 + n;
        gl_lds16(Wz[z] + (size_t)(n0 + ch * 8 + lrow) * C_ + k0 + lcol,
                 base + 8192 + z * 4096 + ch * 512);
      }
  };

  STAGE(0, 0);
  __syncthreads();   // buf0 drained

  for (int i = 0; i < 6; i++) {
    const int bb = i & 1;
    if (i < 5) STAGE(bb ^ 1, (i + 1) * 64);   // async loads fly during compute

    const u16* As = smem + bb * QKV_SBUF;
    const u16* Bs0 = As + 8192;
#pragma unroll
    for (int ks = 0; ks < 2; ks++) {
      short8 af2[2];
#pragma unroll
      for (int mi = 0; mi < 2; mi++)
        af2[mi] = *reinterpret_cast<const short8*>(
            As + (w * 32 + mi * 16 + c) * 64 + (ks * 4 + quad) * 8);
#pragma unroll
      for (int z = 0; z < 3; z++) {
#pragma unroll
        for (int ni = 0; ni < 4; ni++) {
          short8 bf = *reinterpret_cast<const short8*>(
              Bs0 + z * 4096 + (ni * 16 + c) * 64 + (ks * 4 + quad) * 8);
#pragma unroll
          for (int mi = 0; mi < 2; mi++)
            acc[z][mi][ni] = __builtin_amdgcn_mfma_f32_16x16x32_bf16(af2[mi], bf, acc[z][mi][ni], 0, 0, 0);
        }
      }
    }
    if (i < 5) __syncthreads();   // drain vmcnt -> buf[bb^1] ready
  }

  const int bb2 = m0 >> 11;
  const int tbase = m0 & (T_ - 1);

  // ---- V: register scatter to Vt[B][H][D][T] ----
  {
    const size_t vbase = ((size_t)(bb2 * H_ + hh)) * D_ * T_;
#pragma unroll
    for (int mi = 0; mi < 2; mi++) {
      int t = tbase + w * 32 + mi * 16 + quad * 4;
#pragma unroll
      for (int ni = 0; ni < 4; ni++) {
        int d = ni * 16 + c;
        ushort4 pk;
        pk.x = f2b(acc[2][mi][ni][0]); pk.y = f2b(acc[2][mi][ni][1]);
        pk.z = f2b(acc[2][mi][ni][2]); pk.w = f2b(acc[2][mi][ni][3]);
        *reinterpret_cast<ushort4*>(Vto + vbase + (size_t)d * T_ + t) = pk;
      }
    }
  }

  // ---- Q then K: lane-parallel RMS + RoPE, LDS transpose store ----
  u16* Ep = smem;
#pragma unroll
  for (int zz = 0; zz < 2; zz++) {
    __syncthreads();
#pragma unroll
    for (int mi = 0; mi < 2; mi++) {
      float ssr[4];
#pragma unroll
      for (int r = 0; r < 4; r++) {
        float s0 = acc[zz][mi][0][r], s1 = acc[zz][mi][1][r];
        float s2 = acc[zz][mi][2][r], s3 = acc[zz][mi][3][r];
        ssr[r] = s0 * s0 + s1 * s1 + s2 * s2 + s3 * s3;
      }
#pragma unroll
      for (int off = 1; off < 16; off <<= 1)
#pragma unroll
        for (int r = 0; r < 4; r++) ssr[r] += __shfl_xor(ssr[r], off, 64);
      int rowb = w * 32 + mi * 16 + quad * 4;
#pragma unroll
      for (int r = 0; r < 4; r++) {
        float scl = rsqrtf(ssr[r] * (1.0f / 64.0f) + 1e-5f);
        if (zz == 0) scl *= QSCALE;     // fold softmax scale into Q
        int t = tbase + rowb + r;
#pragma unroll
        for (int h2 = 0; h2 < 2; h2++) {
          float cs = cosb[t * 32 + h2 * 16 + c];
          float sn = sinb[t * 32 + h2 * 16 + c];
          float x1 = acc[zz][mi][h2][r];
          float x2 = acc[zz][mi][h2 + 2][r];
          Ep[(rowb + r) * 72 + h2 * 16 + c]       = f2b((x1 * cs + x2 * sn) * scl);
          Ep[(rowb + r) * 72 + (h2 + 2) * 16 + c] = f2b((x2 * cs - x1 * sn) * scl);
        }
      }
    }
    __syncthreads();
    {
      int row = tid >> 1, half = tid & 1;
      int t = tbase + row;
      u16* Og = (zz == 0) ? Qo : Ko;
      u16* dst = Og + (((size_t)(bb2 * H_ + hh)) * T_ + t) * D_ + half * 32;
#pragma unroll
      for (int i = 0; i < 4; i++)
        *reinterpret_cast<uint4*>(dst + i * 8) =
            *reinterpret_cast<const uint4*>(Ep + row * 72 + half * 32 + i * 8);
    }
  }
}

// ---------------------------------------------------------------------------
// MFMA flash attention — round-6 version (best measured; unchanged).
// ---------------------------------------------------------------------------
__global__ __launch_bounds__(256, 3) void attn_mfma(
    const u16* __restrict__ Qg, const u16* __restrict__ Kg,
    const u16* __restrict__ Vtg, u16* __restrict__ Yg)
{
  // two buffers: buf b at smem + b*8192: Ks[4096] | Vs[4096] u16 (32 KB total)
  __shared__ __align__(16) u16 smem[16384];

  const int tid = threadIdx.x;
  const int w = tid >> 6;
  const int lane = tid & 63;
  const int hi = lane >> 5;
  const int lq = lane & 31;

  // XCD remap: 768 wgs = 8 xcds x (6 bh x 16 q-blocks)
  const int id = blockIdx.x;
  const int xcd = id & 7;
  const int slot = id >> 3;              // 0..95
  const int bh = xcd * 6 + (slot >> 4);  // 0..47
  const int q0 = (slot & 15) * 128;

  const size_t baseQK = (size_t)bh * T_ * D_;
  const size_t baseV  = (size_t)bh * D_ * T_;

  // Q fragments (B-operand): lane holds Q[q0+w*32+lq][ds*16 + hi*8 + j]
  short8 qf[4];
  {
    const u16* qp = Qg + baseQK + (size_t)(q0 + w * 32 + lq) * D_ + hi * 8;
#pragma unroll
    for (int d = 0; d < 4; d++)
      qf[d] = *reinterpret_cast<const short8*>(qp + d * 16);
  }

  floatx16 z16;
#pragma unroll
  for (int i = 0; i < 16; i++) z16[i] = 0.f;
  short8 vones;
#pragma unroll
  for (int i = 0; i < 8; i++) vones[i] = (short)0x3F80;

  // staging: 256 threads cover 64 rows x 2 x 16B chunks; R3 slot swizzle
  const int sr = tid >> 2;
  const int sch = tid & 3;
  const int r3s = ((sr & 3) << 1) | ((sr >> 2) & 1);   // R3(sr&7)
  const int ko0 = sr * 64 + ((sch ^ r3s) * 8);
  const int ko1 = sr * 64 + (((sch + 4) ^ r3s) * 8);
  const int vo0 = 4096 + ko0;
  const int vo1 = 4096 + ko1;
  const u16* kga = Kg + baseQK + (size_t)sr * D_ + sch * 8;
  const u16* vga = Vtg + baseV + (size_t)sr * T_ + sch * 8;

  // prologue: tile 0 -> regs -> buf0; then prefetch tile 1 into regs
  uint4 ka = *reinterpret_cast<const uint4*>(kga);
  uint4 kb = *reinterpret_cast<const uint4*>(kga + 32);
  uint4 va = *reinterpret_cast<const uint4*>(vga);
  uint4 vb = *reinterpret_cast<const uint4*>(vga + 32);
  *reinterpret_cast<uint4*>(smem + ko0) = ka;
  *reinterpret_cast<uint4*>(smem + ko1) = kb;
  *reinterpret_cast<uint4*>(smem + vo0) = va;
  *reinterpret_cast<uint4*>(smem + vo1) = vb;
  const u16* kload = kga + (size_t)64 * D_;
  const u16* vload = vga + 64;
  ka = *reinterpret_cast<const uint4*>(kload);
  kb = *reinterpret_cast<const uint4*>(kload + 32);
  va = *reinterpret_cast<const uint4*>(vload);
  vb = *reinterpret_cast<const uint4*>(vload + 32);
  kload += (size_t)64 * D_;
  vload += 64;

  floatx16 o0 = z16, o1 = z16;
  floatx16 l_acc = z16;

  const int r3q = ((lq & 3) << 1) | ((lq >> 2) & 1);   // R3(lq&7)

  // hoisted thread-invariant LDS read offsets
  int koff[2][4], voff[2][4];
#pragma unroll
  for (int ds = 0; ds < 4; ds++) {
    const int xr = (ds * 2 + hi) ^ r3q;
    koff[0][ds] = lq * 64 + xr * 8;
    koff[1][ds] = (32 + lq) * 64 + xr * 8;
    voff[0][ds] = 4096 + lq * 64 + xr * 8;
    voff[1][ds] = 4096 + (32 + lq) * 64 + xr * 8;
  }

  for (int kt = 0; kt < 32; kt++) {
    __syncthreads();   // buf[kt&1] fully written; buf[(kt+1)&1] fully read

    // write prefetched tile kt+1 into the other buffer; issue loads kt+2
    if (kt < 31) {
      u16* wb = smem + (((kt + 1) & 1) << 13);
      *reinterpret_cast<uint4*>(wb + ko0) = ka;
      *reinterpret_cast<uint4*>(wb + ko1) = kb;
      *reinterpret_cast<uint4*>(wb + vo0) = va;
      *reinterpret_cast<uint4*>(wb + vo1) = vb;
      if (kt < 30) {
        ka = *reinterpret_cast<const uint4*>(kload);
        kb = *reinterpret_cast<const uint4*>(kload + 32);
        va = *reinterpret_cast<const uint4*>(vload);
        vb = *reinterpret_cast<const uint4*>(vload + 32);
        kload += (size_t)64 * D_;
        vload += 64;
      }
    }

    const u16* Ksb = smem + ((kt & 1) << 13);

    // ---- QK^T (swapped): st = K * Q^T, col = q (lane-local), rows = t ----
    floatx16 st0, st1;
    __builtin_amdgcn_s_setprio(1);
    {
      short8 kf0 = *reinterpret_cast<const short8*>(Ksb + koff[0][0]);
      short8 kf1 = *reinterpret_cast<const short8*>(Ksb + koff[1][0]);
      st0 = __builtin_amdgcn_mfma_f32_32x32x16_bf16(kf0, qf[0], z16, 0, 0, 0);
      st1 = __builtin_amdgcn_mfma_f32_32x32x16_bf16(kf1, qf[0], z16, 0, 0, 0);
    }
#pragma unroll
    for (int ds = 1; ds < 4; ds++) {
      short8 kf0 = *reinterpret_cast<const short8*>(Ksb + koff[0][ds]);
      short8 kf1 = *reinterpret_cast<const short8*>(Ksb + koff[1][ds]);
      st0 = __builtin_amdgcn_mfma_f32_32x32x16_bf16(kf0, qf[ds], st0, 0, 0, 0);
      st1 = __builtin_amdgcn_mfma_f32_32x32x16_bf16(kf1, qf[ds], st1, 0, 0, 0);
    }
    __builtin_amdgcn_s_setprio(0);

    // ---- softmax: p = exp2(s), bare v_exp_f32 ----
#pragma unroll
    for (int r = 0; r < 16; r++) {
      st0[r] = fexp2(st0[r]);
      st1[r] = fexp2(st1[r]);
    }

    // ---- P -> bf16 A-fragments: 16 v_cvt_pk + 8 permlane32_swap ----
    short8 pa[4];
#pragma unroll
    for (int ks = 0; ks < 4; ks++) {
      const floatx16& s = (ks < 2) ? st0 : st1;
      const int rb = (ks & 1) * 8;
      u32 ca = cvtpk(s[rb + 0], s[rb + 1]);
      u32 cb = cvtpk(s[rb + 2], s[rb + 3]);
      u32 cc = cvtpk(s[rb + 4], s[rb + 5]);
      u32 cd = cvtpk(s[rb + 6], s[rb + 7]);
      plswap(ca, cc);
      plswap(cb, cd);
      short8 pf;
      u32* pfu = reinterpret_cast<u32*>(&pf);
      pfu[0] = ca; pfu[1] = cb; pfu[2] = cc; pfu[3] = cd;
      pa[ks] = pf;
    }

    // ---- PV + l row-sums ----
    __builtin_amdgcn_s_setprio(1);
#pragma unroll
    for (int ks = 0; ks < 4; ks++) {
      short8 vf0 = *reinterpret_cast<const short8*>(Ksb + voff[0][ks]);
      short8 vf1 = *reinterpret_cast<const short8*>(Ksb + voff[1][ks]);
      o0 = __builtin_amdgcn_mfma_f32_32x32x16_bf16(pa[ks], vf0, o0, 0, 0, 0);
      o1 = __builtin_amdgcn_mfma_f32_32x32x16_bf16(pa[ks], vf1, o1, 0, 0, 0);
    }
#pragma unroll
    for (int ks = 0; ks < 4; ks++)
      l_acc = __builtin_amdgcn_mfma_f32_32x32x16_bf16(pa[ks], vones, l_acc, 0, 0, 0);
    __builtin_amdgcn_s_setprio(0);
  }

  // normalization: l_acc[r] holds l for exactly the q-row o[r] holds
  float invr[16];
#pragma unroll
  for (int r = 0; r < 16; r++) invr[r] = __builtin_amdgcn_rcpf(l_acc[r]);

  __syncthreads();   // done with K/V buffers; reuse smem for epilogue
  u16* Ep = smem + w * (32 * 72);
#pragma unroll
  for (int nt = 0; nt < 2; nt++) {
    const floatx16& o = nt ? o1 : o0;
#pragma unroll
    for (int r = 0; r < 16; r++) {
      const int rl = (r & 3) + 8 * (r >> 2) + 4 * hi;
      Ep[rl * 72 + nt * 32 + lq] = f2b(o[r] * invr[r]);
    }
  }
  __syncthreads();
  {
    const int row = tid >> 1, half = tid & 1;   // 128 rows x 2 halves of 64B
    const u16* src = smem + (row >> 5) * (32 * 72) + (row & 31) * 72 + half * 32;
    const int t = q0 + row;
    const int b = bh / H_, h = bh % H_;
    const size_t yi = ((size_t)b * T_ + t) * C_ + (size_t)h * 64 + half * 32;
#pragma unroll
    for (int i = 0; i < 4; i++)
      *reinterpret_cast<uint4*>(Yg + yi + i * 8) =
          *reinterpret_cast<const uint4*>(src + i * 8);
  }
}

// ---------------------------------------------------------------------------
// Out projection — round 7: double-buffered LDS, STAGE-before-compute,
// one barrier per k-step (same schedule fix as qkv).
// Per-buffer: As[128*64] | Bs[64*64] = 12288 u16; 2 buffers = 48 KB.
// ---------------------------------------------------------------------------
#define OUT_SBUF 12288

__global__ __launch_bounds__(256) void out_mfma(
    const u16* __restrict__ Xb, const u16* __restrict__ Wfb, float* __restrict__ Og)
{
  __shared__ __align__(16) u16 smem[2 * OUT_SBUF];   // 48 KB; epilogue reuses 34816 B

  const int id = blockIdx.x;
  const int xcd = id & 7;
  const int s = id >> 3;              // 0..95
  const int m0 = (xcd * 16 + s / 6) * 128;
  const int n0 = (s % 6) * 64;

  const int tid = threadIdx.x;
  const int w = tid >> 6;
  const int lane = tid & 63;
  const int quad = lane >> 4;
  const int c = lane & 15;

  floatx4 acc[2][4];
#pragma unroll
  for (int i = 0; i < 2; i++)
#pragma unroll
    for (int j = 0; j < 4; j++) acc[i][j] = (floatx4){0.f, 0.f, 0.f, 0.f};

  const int lrow = lane >> 3;
  const int lcol = (lane & 7) * 8;

  auto STAGE = [&](int bb, int k0) {
    u16* base = smem + bb * OUT_SBUF;
#pragma unroll
    for (int n = 0; n < 4; n++) {
      const int ch = w * 4 + n;
      gl_lds16(Xb + (size_t)(m0 + ch * 8 + lrow) * C_ + k0 + lcol, base + ch * 512);
    }
#pragma unroll
    for (int n = 0; n < 2; n++) {
      const int ch = w * 2 + n;
      gl_lds16(Wfb + (size_t)(n0 + ch * 8 + lrow) * C_ + k0 + lcol,
               base + 8192 + ch * 512);
    }
  };

  STAGE(0, 0);
  __syncthreads();

  for (int i = 0; i < 6; i++) {
    const int bb = i & 1;
    if (i < 5) STAGE(bb ^ 1, (i + 1) * 64);

    const u16* As = smem + bb * OUT_SBUF;
    const u16* Bs = As + 8192;
#pragma unroll
    for (int ks = 0; ks < 2; ks++) {
      short8 af[2], bf[4];
#pragma unroll
      for (int mi = 0; mi < 2; mi++)
        af[mi] = *reinterpret_cast<const short8*>(
            As + (w * 32 + mi * 16 + c) * 64 + (ks * 4 + quad) * 8);
#pragma unroll
      for (int ni = 0; ni < 4; ni++)
        bf[ni] = *reinterpret_cast<const short8*>(
            Bs + (ni * 16 + c) * 64 + (ks * 4 + quad) * 8);
#pragma unroll
      for (int mi = 0; mi < 2; mi++)
#pragma unroll
        for (int ni = 0; ni < 4; ni++)
          acc[mi][ni] = __builtin_amdgcn_mfma_f32_16x16x32_bf16(af[mi], bf[ni], acc[mi][ni], 0, 0, 0);
    }
    if (i < 5) __syncthreads();
  }

  __syncthreads();
  float* Ep = reinterpret_cast<float*>(smem) + w * (32 * 68);
#pragma unroll
  for (int mi = 0; mi < 2; mi++)
#pragma unroll
    for (int ni = 0; ni < 4; ni++) {
      int rw = mi * 16 + quad * 4;
      int col = ni * 16 + c;
#pragma unroll
      for (int r = 0; r < 4; r++)
        Ep[(rw + r) * 68 + col] = acc[mi][ni][r];
    }
  __syncthreads();
  {
    int rw2 = lane >> 1, half = lane & 1;
    const float* src = Ep + rw2 * 68 + half * 32;
    float* dst = Og + (size_t)(m0 + w * 32 + rw2) * C_ + n0 + half * 32;
#pragma unroll
    for (int i = 0; i < 8; i++)
      *reinterpret_cast<float4*>(dst + i * 4) =
          *reinterpret_cast<const float4*>(src + i * 4);
  }
}

// ---------------------------------------------------------------------------
extern "C" void kernel_launch(void* const* d_in, const int* in_sizes, int n_in,
                              void* d_out, int out_size, void* d_ws, size_t ws_size,
                              hipStream_t stream) {
  (void)in_sizes; (void)n_in; (void)out_size; (void)ws_size;
  const float* x    = (const float*)d_in[0];
  const float* Wq   = (const float*)d_in[1];
  const float* Wk   = (const float*)d_in[2];
  const float* Wv   = (const float*)d_in[3];
  const float* Wo   = (const float*)d_in[4];
  const float* cosb = (const float*)d_in[5];
  const float* sinb = (const float*)d_in[6];

  const size_t MC = (size_t)M_ * C_;    // 6291456
  u16* ws = (u16*)d_ws;
  u16* Q   = ws;                        // [B][H][T][D] bf16 (pre-scaled)
  u16* K   = Q + MC;
  u16* Vt  = K + MC;                    // [B][H][D][T] bf16
  u16* Y   = Vt + MC;                   // attn out [B*T][C] bf16; doubles as Xb
  u16* Xb  = Y;                         // bf16 X (consumed by qkv before attn writes Y)
  u16* Wb  = Y + MC;                    // 4 x 147456 bf16 weights
  u16* Wqb = Wb;
  u16* Wkb = Wb + 147456;
  u16* Wvb = Wb + 2 * 147456;
  u16* Wob = Wb + 3 * 147456;
  float* out = (float*)d_out;

  prep_bf16<<<3360, 256, 0, stream>>>(x, Wq, Wk, Wv, Wo, Xb, Wqb, Wkb, Wvb, Wob);

  qkv_fused<<<768, 256, 0, stream>>>(Xb, Wqb, Wkb, Wvb, cosb, sinb, Q, K, Vt);

  attn_mfma<<<768, 256, 0, stream>>>(Q, K, Vt, Y);

  out_mfma<<<768, 256, 0, stream>>>(Y, Wob, out);
}

// Round 8
// 206.245 us; speedup vs baseline: 1.6733x; 1.0004x over previous
//
#include <hip/hip_runtime.h>
#include <hip/hip_bf16.h>
#include <stdint.h>

#define B_ 8
#define T_ 2048
#define C_ 384
#define H_ 6
#define D_ 64
#define M_ (B_*T_)   // 16384

typedef unsigned short u16;
typedef unsigned int u32;
typedef __attribute__((ext_vector_type(8))) short short8;
typedef __attribute__((ext_vector_type(4))) float floatx4;
typedef __attribute__((ext_vector_type(16))) float floatx16;

// softmax scale folded into stored Q: 0.125 * log2(e)
#define QSCALE 0.18033688011112042f

__device__ __forceinline__ u16 f2b(float f) {
  union { float f; unsigned u; } x; x.f = f;
  unsigned r = x.u + 0x7fffu + ((x.u >> 16) & 1u);  // round-nearest-even
  return (u16)(r >> 16);
}
__device__ __forceinline__ u32 pack_bf16(float a, float b) {
  union { __hip_bfloat162 h; u32 u; } x;
  x.h = __float22bfloat162_rn(float2{a, b});
  return x.u;
}
__device__ __forceinline__ uint4 pack8(const float4& lo, const float4& hi) {
  uint4 r;
  r.x = pack_bf16(lo.x, lo.y); r.y = pack_bf16(lo.z, lo.w);
  r.z = pack_bf16(hi.x, hi.y); r.w = pack_bf16(hi.z, hi.w);
  return r;
}

// v_permlane32_swap_b32: swaps a.hi(32 lanes) <-> b.lo(32 lanes).
__device__ __forceinline__ void plswap(u32& a, u32& b) {
  asm("v_permlane32_swap_b32 %0, %1" : "+v"(a), "+v"(b));
}

// bare v_exp_f32 — no libm range/denormal fixup (inputs bounded: |s|<=11.6)
__device__ __forceinline__ float fexp2(float x) {
#if __has_builtin(__builtin_amdgcn_exp2f)
  return __builtin_amdgcn_exp2f(x);
#else
  float r; asm("v_exp_f32 %0, %1" : "=v"(r) : "v"(x)); return r;
#endif
}

// packed f32x2 -> bf16x2 in ONE instruction (dst.lo = bf16(a), dst.hi = bf16(b))
__device__ __forceinline__ u32 cvtpk(float a, float b) {
  u32 r; asm("v_cvt_pk_bf16_f32 %0, %1, %2" : "=v"(r) : "v"(a), "v"(b)); return r;
}

// async global->LDS, 16B per lane.
__device__ __forceinline__ void gl_lds16(const u16* g, u16* l) {
#if __has_builtin(__builtin_amdgcn_global_load_lds)
  __builtin_amdgcn_global_load_lds(
      (const __attribute__((address_space(1))) unsigned int*)g,
      (__attribute__((address_space(3))) unsigned int*)l,
      16, 0, 0);
#else
  *reinterpret_cast<uint4*>(l + (threadIdx.x & 63) * 8) =
      *reinterpret_cast<const uint4*>(g);
#endif
}

// ---------------------------------------------------------------------------
// prep: one-time fp32 -> bf16 conversion of X and the four weight matrices.
// ---------------------------------------------------------------------------
__global__ __launch_bounds__(256) void prep_bf16(
    const float* __restrict__ x,
    const float* __restrict__ wq, const float* __restrict__ wk,
    const float* __restrict__ wv, const float* __restrict__ wo,
    u16* __restrict__ xb,
    u16* __restrict__ wqb, u16* __restrict__ wkb,
    u16* __restrict__ wvb, u16* __restrict__ wob)
{
  const int c = blockIdx.x * 256 + threadIdx.x;
  const float* src;
  u16* dst;
  int off;
  if (c < 786432) {                 // X: 6291456 / 8
    src = x; dst = xb; off = c;
  } else {
    int t = c - 786432;             // W: 147456 / 8 = 18432 chunks each
    int wsel = t / 18432;
    off = t - wsel * 18432;
    src = (wsel == 0) ? wq : (wsel == 1) ? wk : (wsel == 2) ? wv : wo;
    dst = (wsel == 0) ? wqb : (wsel == 1) ? wkb : (wsel == 2) ? wvb : wob;
  }
  const float4* p = reinterpret_cast<const float4*>(src + (size_t)off * 8);
  float4 lo = p[0], hi = p[1];
  *reinterpret_cast<uint4*>(dst + (size_t)off * 8) = pack8(lo, hi);
}

// ---------------------------------------------------------------------------
// Fused QKV projection — round-7 version (dbuf, STAGE-before-compute).
// ---------------------------------------------------------------------------
#define QKV_SBUF 20480

__global__ __launch_bounds__(256) void qkv_fused(
    const u16* __restrict__ Xb,
    const u16* __restrict__ Wqb, const u16* __restrict__ Wkb, const u16* __restrict__ Wvb,
    const float* __restrict__ cosb, const float* __restrict__ sinb,
    u16* __restrict__ Qo, u16* __restrict__ Ko, u16* __restrict__ Vto)
{
  __shared__ __align__(16) u16 smem[2 * QKV_SBUF];   // 80 KB

  // XCD remap: 768 wgs = 8 xcds x (16 m-blocks x 6 heads)
  const int id = blockIdx.x;
  const int xcd = id & 7;
  const int s = id >> 3;              // 0..95
  const int mb = xcd * 16 + s / 6;    // 0..127
  const int hh = s % 6;
  const int m0 = mb * 128;
  const int n0 = hh * 64;

  const int tid = threadIdx.x;
  const int w = tid >> 6;
  const int lane = tid & 63;
  const int quad = lane >> 4;
  const int c = lane & 15;

  const u16* Wz[3] = {Wqb, Wkb, Wvb};

  floatx4 acc[3][2][4];
#pragma unroll
  for (int z = 0; z < 3; z++)
#pragma unroll
    for (int i = 0; i < 2; i++)
#pragma unroll
      for (int j = 0; j < 4; j++) acc[z][i][j] = (floatx4){0.f, 0.f, 0.f, 0.f};

  const int lrow = lane >> 3;        // row within an 8-row chunk
  const int lcol = (lane & 7) * 8;   // 8-col (16B) offset

  auto STAGE = [&](int bb, int k0) {
    u16* base = smem + bb * QKV_SBUF;
#pragma unroll
    for (int n = 0; n < 4; n++) {
      const int ch = w * 4 + n;
      gl_lds16(Xb + (size_t)(m0 + ch * 8 + lrow) * C_ + k0 + lcol, base + ch * 512);
    }
#pragma unroll
    for (int z = 0; z < 3; z++)
#pragma unroll
      for (int n = 0; n < 2; n++) {
        const int ch = w * 2 + n;
        gl_lds16(Wz[z] + (size_t)(n0 + ch * 8 + lrow) * C_ + k0 + lcol,
                 base + 8192 + z * 4096 + ch * 512);
      }
  };

  STAGE(0, 0);
  __syncthreads();   // buf0 drained

  for (int i = 0; i < 6; i++) {
    const int bb = i & 1;
    if (i < 5) STAGE(bb ^ 1, (i + 1) * 64);   // async loads fly during compute

    const u16* As = smem + bb * QKV_SBUF;
    const u16* Bs0 = As + 8192;
#pragma unroll
    for (int ks = 0; ks < 2; ks++) {
      short8 af2[2];
#pragma unroll
      for (int mi = 0; mi < 2; mi++)
        af2[mi] = *reinterpret_cast<const short8*>(
            As + (w * 32 + mi * 16 + c) * 64 + (ks * 4 + quad) * 8);
#pragma unroll
      for (int z = 0; z < 3; z++) {
#pragma unroll
        for (int ni = 0; ni < 4; ni++) {
          short8 bf = *reinterpret_cast<const short8*>(
              Bs0 + z * 4096 + (ni * 16 + c) * 64 + (ks * 4 + quad) * 8);
#pragma unroll
          for (int mi = 0; mi < 2; mi++)
            acc[z][mi][ni] = __builtin_amdgcn_mfma_f32_16x16x32_bf16(af2[mi], bf, acc[z][mi][ni], 0, 0, 0);
        }
      }
    }
    if (i < 5) __syncthreads();   // drain vmcnt -> buf[bb^1] ready
  }

  const int bb2 = m0 >> 11;
  const int tbase = m0 & (T_ - 1);

  // ---- V: register scatter to Vt[B][H][D][T] ----
  {
    const size_t vbase = ((size_t)(bb2 * H_ + hh)) * D_ * T_;
#pragma unroll
    for (int mi = 0; mi < 2; mi++) {
      int t = tbase + w * 32 + mi * 16 + quad * 4;
#pragma unroll
      for (int ni = 0; ni < 4; ni++) {
        int d = ni * 16 + c;
        ushort4 pk;
        pk.x = f2b(acc[2][mi][ni][0]); pk.y = f2b(acc[2][mi][ni][1]);
        pk.z = f2b(acc[2][mi][ni][2]); pk.w = f2b(acc[2][mi][ni][3]);
        *reinterpret_cast<ushort4*>(Vto + vbase + (size_t)d * T_ + t) = pk;
      }
    }
  }

  // ---- Q then K: lane-parallel RMS + RoPE, LDS transpose store ----
  u16* Ep = smem;
#pragma unroll
  for (int zz = 0; zz < 2; zz++) {
    __syncthreads();
#pragma unroll
    for (int mi = 0; mi < 2; mi++) {
      float ssr[4];
#pragma unroll
      for (int r = 0; r < 4; r++) {
        float s0 = acc[zz][mi][0][r], s1 = acc[zz][mi][1][r];
        float s2 = acc[zz][mi][2][r], s3 = acc[zz][mi][3][r];
        ssr[r] = s0 * s0 + s1 * s1 + s2 * s2 + s3 * s3;
      }
#pragma unroll
      for (int off = 1; off < 16; off <<= 1)
#pragma unroll
        for (int r = 0; r < 4; r++) ssr[r] += __shfl_xor(ssr[r], off, 64);
      int rowb = w * 32 + mi * 16 + quad * 4;
#pragma unroll
      for (int r = 0; r < 4; r++) {
        float scl = rsqrtf(ssr[r] * (1.0f / 64.0f) + 1e-5f);
        if (zz == 0) scl *= QSCALE;     // fold softmax scale into Q
        int t = tbase + rowb + r;
#pragma unroll
        for (int h2 = 0; h2 < 2; h2++) {
          float cs = cosb[t * 32 + h2 * 16 + c];
          float sn = sinb[t * 32 + h2 * 16 + c];
          float x1 = acc[zz][mi][h2][r];
          float x2 = acc[zz][mi][h2 + 2][r];
          Ep[(rowb + r) * 72 + h2 * 16 + c]       = f2b((x1 * cs + x2 * sn) * scl);
          Ep[(rowb + r) * 72 + (h2 + 2) * 16 + c] = f2b((x2 * cs - x1 * sn) * scl);
        }
      }
    }
    __syncthreads();
    {
      int row = tid >> 1, half = tid & 1;
      int t = tbase + row;
      u16* Og = (zz == 0) ? Qo : Ko;
      u16* dst = Og + (((size_t)(bb2 * H_ + hh)) * T_ + t) * D_ + half * 32;
#pragma unroll
      for (int i = 0; i < 4; i++)
        *reinterpret_cast<uint4*>(dst + i * 8) =
            *reinterpret_cast<const uint4*>(Ep + row * 72 + half * 32 + i * 8);
    }
  }
}

// ---------------------------------------------------------------------------
// MFMA flash attention — round 8:
//  (a) l via VALU adds folded into the exp loop (removes the 4-MFMA ones
//      chain: 20% of matrix work + ~280 serial cyc/tile); inv redistributed
//      once at the end via 16 shuffles (round-1 proven pattern).
//  (b) critical-path reorder: QK ds_reads+MFMA FIRST after the barrier;
//      next-tile ds_writes + global loads issued after (complete under
//      exp/cvt/PV instead of stalling the first kf read via lgkm ordering).
// ---------------------------------------------------------------------------
__global__ __launch_bounds__(256, 3) void attn_mfma(
    const u16* __restrict__ Qg, const u16* __restrict__ Kg,
    const u16* __restrict__ Vtg, u16* __restrict__ Yg)
{
  // two buffers: buf b at smem + b*8192: Ks[4096] | Vs[4096] u16 (32 KB total)
  __shared__ __align__(16) u16 smem[16384];

  const int tid = threadIdx.x;
  const int w = tid >> 6;
  const int lane = tid & 63;
  const int hi = lane >> 5;
  const int lq = lane & 31;

  // XCD remap: 768 wgs = 8 xcds x (6 bh x 16 q-blocks)
  const int id = blockIdx.x;
  const int xcd = id & 7;
  const int slot = id >> 3;              // 0..95
  const int bh = xcd * 6 + (slot >> 4);  // 0..47
  const int q0 = (slot & 15) * 128;

  const size_t baseQK = (size_t)bh * T_ * D_;
  const size_t baseV  = (size_t)bh * D_ * T_;

  // Q fragments (B-operand): lane holds Q[q0+w*32+lq][ds*16 + hi*8 + j]
  short8 qf[4];
  {
    const u16* qp = Qg + baseQK + (size_t)(q0 + w * 32 + lq) * D_ + hi * 8;
#pragma unroll
    for (int d = 0; d < 4; d++)
      qf[d] = *reinterpret_cast<const short8*>(qp + d * 16);
  }

  floatx16 z16;
#pragma unroll
  for (int i = 0; i < 16; i++) z16[i] = 0.f;

  // staging: 256 threads cover 64 rows x 2 x 16B chunks; R3 slot swizzle
  const int sr = tid >> 2;
  const int sch = tid & 3;
  const int r3s = ((sr & 3) << 1) | ((sr >> 2) & 1);   // R3(sr&7)
  const int ko0 = sr * 64 + ((sch ^ r3s) * 8);
  const int ko1 = sr * 64 + (((sch + 4) ^ r3s) * 8);
  const int vo0 = 4096 + ko0;
  const int vo1 = 4096 + ko1;
  const u16* kga = Kg + baseQK + (size_t)sr * D_ + sch * 8;
  const u16* vga = Vtg + baseV + (size_t)sr * T_ + sch * 8;

  // prologue: tile 0 -> regs -> buf0; then prefetch tile 1 into regs
  uint4 ka = *reinterpret_cast<const uint4*>(kga);
  uint4 kb = *reinterpret_cast<const uint4*>(kga + 32);
  uint4 va = *reinterpret_cast<const uint4*>(vga);
  uint4 vb = *reinterpret_cast<const uint4*>(vga + 32);
  *reinterpret_cast<uint4*>(smem + ko0) = ka;
  *reinterpret_cast<uint4*>(smem + ko1) = kb;
  *reinterpret_cast<uint4*>(smem + vo0) = va;
  *reinterpret_cast<uint4*>(smem + vo1) = vb;
  const u16* kload = kga + (size_t)64 * D_;
  const u16* vload = vga + 64;
  ka = *reinterpret_cast<const uint4*>(kload);
  kb = *reinterpret_cast<const uint4*>(kload + 32);
  va = *reinterpret_cast<const uint4*>(vload);
  vb = *reinterpret_cast<const uint4*>(vload + 32);
  kload += (size_t)64 * D_;
  vload += 64;

  floatx16 o0 = z16, o1 = z16;
  float l_part = 0.0f;

  const int r3q = ((lq & 3) << 1) | ((lq >> 2) & 1);   // R3(lq&7)

  // hoisted thread-invariant LDS read offsets
  int koff[2][4], voff[2][4];
#pragma unroll
  for (int ds = 0; ds < 4; ds++) {
    const int xr = (ds * 2 + hi) ^ r3q;
    koff[0][ds] = lq * 64 + xr * 8;
    koff[1][ds] = (32 + lq) * 64 + xr * 8;
    voff[0][ds] = 4096 + lq * 64 + xr * 8;
    voff[1][ds] = 4096 + (32 + lq) * 64 + xr * 8;
  }

  for (int kt = 0; kt < 32; kt++) {
    __syncthreads();   // buf[kt&1] fully written; buf[(kt+1)&1] fully read

    const u16* Ksb = smem + ((kt & 1) << 13);

    // ---- QK^T FIRST (critical path: reads issue right after barrier) ----
    floatx16 st0, st1;
    __builtin_amdgcn_s_setprio(1);
    {
      short8 kf0 = *reinterpret_cast<const short8*>(Ksb + koff[0][0]);
      short8 kf1 = *reinterpret_cast<const short8*>(Ksb + koff[1][0]);
      st0 = __builtin_amdgcn_mfma_f32_32x32x16_bf16(kf0, qf[0], z16, 0, 0, 0);
      st1 = __builtin_amdgcn_mfma_f32_32x32x16_bf16(kf1, qf[0], z16, 0, 0, 0);
    }
#pragma unroll
    for (int ds = 1; ds < 4; ds++) {
      short8 kf0 = *reinterpret_cast<const short8*>(Ksb + koff[0][ds]);
      short8 kf1 = *reinterpret_cast<const short8*>(Ksb + koff[1][ds]);
      st0 = __builtin_amdgcn_mfma_f32_32x32x16_bf16(kf0, qf[ds], st0, 0, 0, 0);
      st1 = __builtin_amdgcn_mfma_f32_32x32x16_bf16(kf1, qf[ds], st1, 0, 0, 0);
    }
    __builtin_amdgcn_s_setprio(0);

    // ---- stage writes (kt+1) + issue loads (kt+2): complete under VALU ----
    if (kt < 31) {
      u16* wb = smem + (((kt + 1) & 1) << 13);
      *reinterpret_cast<uint4*>(wb + ko0) = ka;
      *reinterpret_cast<uint4*>(wb + ko1) = kb;
      *reinterpret_cast<uint4*>(wb + vo0) = va;
      *reinterpret_cast<uint4*>(wb + vo1) = vb;
      if (kt < 30) {
        ka = *reinterpret_cast<const uint4*>(kload);
        kb = *reinterpret_cast<const uint4*>(kload + 32);
        va = *reinterpret_cast<const uint4*>(vload);
        vb = *reinterpret_cast<const uint4*>(vload + 32);
        kload += (size_t)64 * D_;
        vload += 64;
      }
    }

    // ---- softmax: p = exp2(s), bare v_exp_f32; l summed in-lane ----
#pragma unroll
    for (int r = 0; r < 16; r++) {
      float p0 = fexp2(st0[r]);
      float p1 = fexp2(st1[r]);
      st0[r] = p0;
      st1[r] = p1;
      l_part += p0 + p1;
    }

    // ---- P -> bf16 A-fragments: 16 v_cvt_pk + 8 permlane32_swap ----
    short8 pa[4];
#pragma unroll
    for (int ks = 0; ks < 4; ks++) {
      const floatx16& s = (ks < 2) ? st0 : st1;
      const int rb = (ks & 1) * 8;
      u32 ca = cvtpk(s[rb + 0], s[rb + 1]);
      u32 cb = cvtpk(s[rb + 2], s[rb + 3]);
      u32 cc = cvtpk(s[rb + 4], s[rb + 5]);
      u32 cd = cvtpk(s[rb + 6], s[rb + 7]);
      plswap(ca, cc);
      plswap(cb, cd);
      short8 pf;
      u32* pfu = reinterpret_cast<u32*>(&pf);
      pfu[0] = ca; pfu[1] = cb; pfu[2] = cc; pfu[3] = cd;
      pa[ks] = pf;
    }

    // ---- PV ----
    __builtin_amdgcn_s_setprio(1);
#pragma unroll
    for (int ks = 0; ks < 4; ks++) {
      short8 vf0 = *reinterpret_cast<const short8*>(Ksb + voff[0][ks]);
      short8 vf1 = *reinterpret_cast<const short8*>(Ksb + voff[1][ks]);
      o0 = __builtin_amdgcn_mfma_f32_32x32x16_bf16(pa[ks], vf0, o0, 0, 0, 0);
      o1 = __builtin_amdgcn_mfma_f32_32x32x16_bf16(pa[ks], vf1, o1, 0, 0, 0);
    }
    __builtin_amdgcn_s_setprio(0);
  }

  // l for q=lq: halves hold disjoint t partial sums
  float l_full = l_part + __shfl_xor(l_part, 32, 64);
  float inv = __builtin_amdgcn_rcpf(l_full);

  // redistribute inv to the q-row each accumulator register holds
  float invr[16];
#pragma unroll
  for (int r = 0; r < 16; r++) {
    const int qr = (r & 3) + 8 * (r >> 2) + 4 * hi;
    invr[r] = __shfl(inv, qr, 64);
  }

  __syncthreads();   // done with K/V buffers; reuse smem for epilogue
  u16* Ep = smem + w * (32 * 72);
#pragma unroll
  for (int nt = 0; nt < 2; nt++) {
    const floatx16& o = nt ? o1 : o0;
#pragma unroll
    for (int r = 0; r < 16; r++) {
      const int rl = (r & 3) + 8 * (r >> 2) + 4 * hi;
      Ep[rl * 72 + nt * 32 + lq] = f2b(o[r] * invr[r]);
    }
  }
  __syncthreads();
  {
    const int row = tid >> 1, half = tid & 1;   // 128 rows x 2 halves of 64B
    const u16* src = smem + (row >> 5) * (32 * 72) + (row & 31) * 72 + half * 32;
    const int t = q0 + row;
    const int b = bh / H_, h = bh % H_;
    const size_t yi = ((size_t)b * T_ + t) * C_ + (size_t)h * 64 + half * 32;
#pragma unroll
    for (int i = 0; i < 4; i++)
      *reinterpret_cast<uint4*>(Yg + yi + i * 8) =
          *reinterpret_cast<const uint4*>(src + i * 8);
  }
}

// ---------------------------------------------------------------------------
// Out projection — round-7 version (dbuf, STAGE-before-compute).
// ---------------------------------------------------------------------------
#define OUT_SBUF 12288

__global__ __launch_bounds__(256) void out_mfma(
    const u16* __restrict__ Xb, const u16* __restrict__ Wfb, float* __restrict__ Og)
{
  __shared__ __align__(16) u16 smem[2 * OUT_SBUF];   // 48 KB; epilogue reuses 34816 B

  const int id = blockIdx.x;
  const int xcd = id & 7;
  const int s = id >> 3;              // 0..95
  const int m0 = (xcd * 16 + s / 6) * 128;
  const int n0 = (s % 6) * 64;

  const int tid = threadIdx.x;
  const int w = tid >> 6;
  const int lane = tid & 63;
  const int quad = lane >> 4;
  const int c = lane & 15;

  floatx4 acc[2][4];
#pragma unroll
  for (int i = 0; i < 2; i++)
#pragma unroll
    for (int j = 0; j < 4; j++) acc[i][j] = (floatx4){0.f, 0.f, 0.f, 0.f};

  const int lrow = lane >> 3;
  const int lcol = (lane & 7) * 8;

  auto STAGE = [&](int bb, int k0) {
    u16* base = smem + bb * OUT_SBUF;
#pragma unroll
    for (int n = 0; n < 4; n++) {
      const int ch = w * 4 + n;
      gl_lds16(Xb + (size_t)(m0 + ch * 8 + lrow) * C_ + k0 + lcol, base + ch * 512);
    }
#pragma unroll
    for (int n = 0; n < 2; n++) {
      const int ch = w * 2 + n;
      gl_lds16(Wfb + (size_t)(n0 + ch * 8 + lrow) * C_ + k0 + lcol,
               base + 8192 + ch * 512);
    }
  };

  STAGE(0, 0);
  __syncthreads();

  for (int i = 0; i < 6; i++) {
    const int bb = i & 1;
    if (i < 5) STAGE(bb ^ 1, (i + 1) * 64);

    const u16* As = smem + bb * OUT_SBUF;
    const u16* Bs = As + 8192;
#pragma unroll
    for (int ks = 0; ks < 2; ks++) {
      short8 af[2], bf[4];
#pragma unroll
      for (int mi = 0; mi < 2; mi++)
        af[mi] = *reinterpret_cast<const short8*>(
            As + (w * 32 + mi * 16 + c) * 64 + (ks * 4 + quad) * 8);
#pragma unroll
      for (int ni = 0; ni < 4; ni++)
        bf[ni] = *reinterpret_cast<const short8*>(
            Bs + (ni * 16 + c) * 64 + (ks * 4 + quad) * 8);
#pragma unroll
      for (int mi = 0; mi < 2; mi++)
#pragma unroll
        for (int ni = 0; ni < 4; ni++)
          acc[mi][ni] = __builtin_amdgcn_mfma_f32_16x16x32_bf16(af[mi], bf[ni], acc[mi][ni], 0, 0, 0);
    }
    if (i < 5) __syncthreads();
  }

  __syncthreads();
  float* Ep = reinterpret_cast<float*>(smem) + w * (32 * 68);
#pragma unroll
  for (int mi = 0; mi < 2; mi++)
#pragma unroll
    for (int ni = 0; ni < 4; ni++) {
      int rw = mi * 16 + quad * 4;
      int col = ni * 16 + c;
#pragma unroll
      for (int r = 0; r < 4; r++)
        Ep[(rw + r) * 68 + col] = acc[mi][ni][r];
    }
  __syncthreads();
  {
    int rw2 = lane >> 1, half = lane & 1;
    const float* src = Ep + rw2 * 68 + half * 32;
    float* dst = Og + (size_t)(m0 + w * 32 + rw2) * C_ + n0 + half * 32;
#pragma unroll
    for (int i = 0; i < 8; i++)
      *reinterpret_cast<float4*>(dst + i * 4) =
          *reinterpret_cast<const float4*>(src + i * 4);
  }
}

// ---------------------------------------------------------------------------
extern "C" void kernel_launch(void* const* d_in, const int* in_sizes, int n_in,
                              void* d_out, int out_size, void* d_ws, size_t ws_size,
                              hipStream_t stream) {
  (void)in_sizes; (void)n_in; (void)out_size; (void)ws_size;
  const float* x    = (const float*)d_in[0];
  const float* Wq   = (const float*)d_in[1];
  const float* Wk   = (const float*)d_in[2];
  const float* Wv   = (const float*)d_in[3];
  const float* Wo   = (const float*)d_in[4];
  const float* cosb = (const float*)d_in[5];
  const float* sinb = (const float*)d_in[6];

  const size_t MC = (size_t)M_ * C_;    // 6291456
  u16* ws = (u16*)d_ws;
  u16* Q   = ws;                        // [B][H][T][D] bf16 (pre-scaled)
  u16* K   = Q + MC;
  u16* Vt  = K + MC;                    // [B][H][D][T] bf16
  u16* Y   = Vt + MC;                   // attn out [B*T][C] bf16; doubles as Xb
  u16* Xb  = Y;                         // bf16 X (consumed by qkv before attn writes Y)
  u16* Wb  = Y + MC;                    // 4 x 147456 bf16 weights
  u16* Wqb = Wb;
  u16* Wkb = Wb + 147456;
  u16* Wvb = Wb + 2 * 147456;
  u16* Wob = Wb + 3 * 147456;
  float* out = (float*)d_out;

  prep_bf16<<<3360, 256, 0, stream>>>(x, Wq, Wk, Wv, Wo, Xb, Wqb, Wkb, Wvb, Wob);

  qkv_fused<<<768, 256, 0, stream>>>(Xb, Wqb, Wkb, Wvb, cosb, sinb, Q, K, Vt);

  attn_mfma<<<768, 256, 0, stream>>>(Q, K, Vt, Y);

  out_mfma<<<768, 256, 0, stream>>>(Y, Wob, out);
}